// Round 4
// baseline (450.678 us; speedup 1.0000x reference)
//
#include <hip/hip_runtime.h>
#include <hip/hip_fp16.h>

#define RES 300
#define NC 48
#define RES2 (RES * RES)
#define NBINS 32768  // 32^3 Morton cells
#define TPP 18       // threads per point: 3 planes x 6 groups of 8 channels

typedef float f32x4 __attribute__((ext_vector_type(4)));
typedef unsigned int u32x4 __attribute__((ext_vector_type(4)));

struct alignas(8)  h4 { __half2 h[2]; };
struct alignas(16) h8 { __half2 h[4]; };

__device__ __forceinline__ int clampi(int v, int lo, int hi) {
    return v < lo ? lo : (v > hi ? hi : v);
}

// spread 5 bits: bit i -> bit 3i
__device__ __forceinline__ unsigned spread5(unsigned v) {
    v &= 31u;
    v = (v | (v << 8)) & 0x100Fu;
    v = (v | (v << 4)) & 0x10C3u;
    v = (v | (v << 2)) & 0x1249u;
    return v;
}

__device__ __forceinline__ unsigned morton_key(float a, float b, float c) {
    int ca = clampi((int)(a * 32.0f), 0, 31);
    int cb = clampi((int)(b * 32.0f), 0, 31);
    int cc = clampi((int)(c * 32.0f), 0, 31);
    return spread5((unsigned)ca) | (spread5((unsigned)cb) << 1) | (spread5((unsigned)cc) << 2);
}

// ---------------- table transpose (fp32 channel-major -> fp16 channel-last) ----------------

__global__ __launch_bounds__(256) void tp_planes_kernel(const float* __restrict__ in,
                                                        __half* __restrict__ out) {
    unsigned idx = blockIdx.x * 256u + threadIdx.x;
    if (idx >= 3u * RES2) return;
    unsigned p  = idx / RES2;
    unsigned yx = idx - p * RES2;
    const float* src = in + (size_t)p * NC * RES2 + yx;
    unsigned short v[NC];
#pragma unroll
    for (int c = 0; c < NC; ++c) {
        __half h = __float2half(src[(size_t)c * RES2]);
        v[c] = *reinterpret_cast<unsigned short*>(&h);
    }
    u32x4* dst = reinterpret_cast<u32x4*>(out + (size_t)idx * NC);
#pragma unroll
    for (int i = 0; i < 6; ++i) {
        u32x4 w;
        w.x = (unsigned)v[8 * i + 0] | ((unsigned)v[8 * i + 1] << 16);
        w.y = (unsigned)v[8 * i + 2] | ((unsigned)v[8 * i + 3] << 16);
        w.z = (unsigned)v[8 * i + 4] | ((unsigned)v[8 * i + 5] << 16);
        w.w = (unsigned)v[8 * i + 6] | ((unsigned)v[8 * i + 7] << 16);
        dst[i] = w;
    }
}

__global__ __launch_bounds__(256) void tp_lines_kernel(const float* __restrict__ in,
                                                       __half* __restrict__ out) {
    unsigned idx = blockIdx.x * 256u + threadIdx.x;
    if (idx >= 3u * RES) return;
    unsigned p = idx / RES;
    unsigned y = idx - p * RES;
#pragma unroll
    for (int c = 0; c < NC; ++c)
        out[(size_t)idx * NC + c] = __float2half(in[((size_t)p * NC + c) * RES + y]);
}

// ---------------- Morton counting sort ----------------

__global__ __launch_bounds__(256) void zero_bins_kernel(unsigned* __restrict__ counts) {
    unsigned i = blockIdx.x * 256u + threadIdx.x;
    if (i < NBINS) counts[i] = 0u;
}

__global__ __launch_bounds__(256) void hist_kernel(const float* __restrict__ x,
                                                   unsigned* __restrict__ counts,
                                                   unsigned N) {
    unsigned i = blockIdx.x * 256u + threadIdx.x;
    if (i >= N) return;
    unsigned k = morton_key(x[3u * i], x[3u * i + 1u], x[3u * i + 2u]);
    atomicAdd(&counts[k], 1u);
}

// one block, 1024 threads; exclusive scan of NBINS counts -> offs
__global__ __launch_bounds__(1024) void scan_kernel(const unsigned* __restrict__ counts,
                                                    unsigned* __restrict__ offs) {
    __shared__ unsigned part[1024];
    int t = threadIdx.x;
    unsigned local[NBINS / 1024];
    unsigned s = 0;
#pragma unroll
    for (int j = 0; j < NBINS / 1024; ++j) {
        local[j] = counts[t * (NBINS / 1024) + j];
        s += local[j];
    }
    part[t] = s;
    __syncthreads();
    for (int d = 1; d < 1024; d <<= 1) {
        unsigned v = (t >= d) ? part[t - d] : 0u;
        __syncthreads();
        part[t] += v;
        __syncthreads();
    }
    unsigned run = (t == 0) ? 0u : part[t - 1];
#pragma unroll
    for (int j = 0; j < NBINS / 1024; ++j) {
        offs[t * (NBINS / 1024) + j] = run;
        run += local[j];
    }
}

// scatter points into Morton order; offs is consumed (becomes end offsets)
__global__ __launch_bounds__(256) void scatter_kernel(const float* __restrict__ x,
                                                      unsigned* __restrict__ offs,
                                                      f32x4* __restrict__ sorted,
                                                      unsigned N) {
    unsigned i = blockIdx.x * 256u + threadIdx.x;
    if (i >= N) return;
    float a = x[3u * i], b = x[3u * i + 1u], c = x[3u * i + 2u];
    unsigned k = morton_key(a, b, c);
    unsigned pos = atomicAdd(&offs[k], 1u);
    f32x4 v;
    v.x = a; v.y = b; v.z = c; v.w = __uint_as_float(i);
    sorted[pos] = v;
}

// ---------------- encode (sorted, 18 threads/pt, 16B gathers, XCD-chunked) ----------------

__global__ __launch_bounds__(256) void encode_sorted_kernel(const f32x4* __restrict__ sorted,
                                                            const __half* __restrict__ pt,  // (3,RES,RES,NC)
                                                            const __half* __restrict__ lt,  // (3,RES,NC)
                                                            float* __restrict__ out,
                                                            unsigned N) {
    // bijective XCD chunking: each XCD gets a contiguous chunk of the
    // Morton-sorted point range -> per-XCD L2 working set ~1 octant of the table.
    unsigned nwg  = gridDim.x;
    unsigned orig = blockIdx.x;
    unsigned xcd = orig & 7u, j = orig >> 3u;
    unsigned qq = nwg >> 3u, r = nwg & 7u;
    unsigned bid = (xcd < r ? xcd * (qq + 1u) : r * (qq + 1u) + (xcd - r) * qq) + j;

    unsigned gid = bid * 256u + threadIdx.x;
    if (gid >= N * TPP) return;
    unsigned s = gid / TPP;
    unsigned q = gid - s * TPP;
    unsigned p = q / 6u;       // plane
    unsigned g = q - p * 6u;   // 8-channel group

    f32x4 pv4 = sorted[s];
    float xv0 = pv4.x, xv1 = pv4.y, xv2 = pv4.z;
    unsigned n = __float_as_uint(pv4.w);

    // p=0: gx=xs0 gy=xs1 gl=xs2 ; p=1: gx=xs0 gy=xs2 gl=xs1 ; p=2: gx=xs1 gy=xs2 gl=xs0
    float gxv = (p == 2u) ? xv1 : xv0;
    float gyv = (p == 0u) ? xv1 : xv2;
    float glv = (p == 0u) ? xv2 : ((p == 1u) ? xv1 : xv0);

    float gxs = 2.0f * gxv - 1.0f;
    float gys = 2.0f * gyv - 1.0f;
    float gls = 2.0f * glv - 1.0f;
    float px = (gxs + 1.0f) * 0.5f * (float)(RES - 1);
    float py = (gys + 1.0f) * 0.5f * (float)(RES - 1);
    float pl = (gls + 1.0f) * 0.5f * (float)(RES - 1);

    float x0f = floorf(px), y0f = floorf(py), l0f = floorf(pl);
    float wx = px - x0f, wy = py - y0f, wl = pl - l0f;

    int ix0 = clampi((int)x0f, 0, RES - 1);
    int ix1 = ix0 + 1 > RES - 1 ? RES - 1 : ix0 + 1;
    int iy0 = clampi((int)y0f, 0, RES - 1);
    int iy1 = iy0 + 1 > RES - 1 ? RES - 1 : iy0 + 1;
    int il0 = clampi((int)l0f, 0, RES - 1);
    int il1 = il0 + 1 > RES - 1 ? RES - 1 : il0 + 1;

    unsigned cbase = g * 8u;
    const __half* pb = pt + (size_t)p * RES2 * NC;
    unsigned o00 = ((unsigned)iy0 * RES + (unsigned)ix0) * NC + cbase;
    unsigned o01 = ((unsigned)iy0 * RES + (unsigned)ix1) * NC + cbase;
    unsigned o10 = ((unsigned)iy1 * RES + (unsigned)ix0) * NC + cbase;
    unsigned o11 = ((unsigned)iy1 * RES + (unsigned)ix1) * NC + cbase;

    h8 v00 = *reinterpret_cast<const h8*>(pb + o00);
    h8 v01 = *reinterpret_cast<const h8*>(pb + o01);
    h8 v10 = *reinterpret_cast<const h8*>(pb + o10);
    h8 v11 = *reinterpret_cast<const h8*>(pb + o11);

    const __half* lb = lt + (size_t)p * RES * NC + cbase;
    h8 vl0 = *reinterpret_cast<const h8*>(lb + (size_t)il0 * NC);
    h8 vl1 = *reinterpret_cast<const h8*>(lb + (size_t)il1 * NC);

    float w00 = (1.0f - wx) * (1.0f - wy);
    float w01 = wx * (1.0f - wy);
    float w10 = (1.0f - wx) * wy;
    float w11 = wx * wy;
    float wl0 = 1.0f - wl;

    f32x4 r0, r1;
#pragma unroll
    for (int jj = 0; jj < 4; ++jj) {
        float2 a00 = __half22float2(v00.h[jj]);
        float2 a01 = __half22float2(v01.h[jj]);
        float2 a10 = __half22float2(v10.h[jj]);
        float2 a11 = __half22float2(v11.h[jj]);
        float2 b0  = __half22float2(vl0.h[jj]);
        float2 b1  = __half22float2(vl1.h[jj]);
        float pvx = a00.x * w00 + a01.x * w01 + a10.x * w10 + a11.x * w11;
        float pvy = a00.y * w00 + a01.y * w01 + a10.y * w10 + a11.y * w11;
        float lvx = b0.x * wl0 + b1.x * wl;
        float lvy = b0.y * wl0 + b1.y * wl;
        float rx = pvx * lvx;
        float ry = pvy * lvy;
        if (jj < 2) {
            if (jj == 0) { r0.x = rx; r0.y = ry; } else { r0.z = rx; r0.w = ry; }
        } else {
            if (jj == 2) { r1.x = rx; r1.y = ry; } else { r1.z = rx; r1.w = ry; }
        }
    }

    float* ob = out + (size_t)n * 144u + p * 48u + g * 8u;
    __builtin_nontemporal_store(r0, reinterpret_cast<f32x4*>(ob));
    __builtin_nontemporal_store(r1, reinterpret_cast<f32x4*>(ob + 4));
}

// ---------------- unsorted encode (fallback when ws fits only tables) ----------------

__global__ __launch_bounds__(256) void encode_kernel(const float* __restrict__ x,
                                                     const __half* __restrict__ pt,
                                                     const __half* __restrict__ lt,
                                                     float* __restrict__ out,
                                                     unsigned N) {
    unsigned gid = blockIdx.x * 256u + threadIdx.x;
    if (gid >= N * 36u) return;
    unsigned n  = gid / 36u;
    unsigned q  = gid - n * 36u;
    unsigned p  = q / 12u;
    unsigned c4 = q - p * 12u;

    float xv0 = x[3u * n + 0u];
    float xv1 = x[3u * n + 1u];
    float xv2 = x[3u * n + 2u];
    float gxv = (p == 2u) ? xv1 : xv0;
    float gyv = (p == 0u) ? xv1 : xv2;
    float glv = (p == 0u) ? xv2 : ((p == 1u) ? xv1 : xv0);

    float gxs = 2.0f * gxv - 1.0f;
    float gys = 2.0f * gyv - 1.0f;
    float gls = 2.0f * glv - 1.0f;
    float px = (gxs + 1.0f) * 0.5f * (float)(RES - 1);
    float py = (gys + 1.0f) * 0.5f * (float)(RES - 1);
    float pl = (gls + 1.0f) * 0.5f * (float)(RES - 1);

    float x0f = floorf(px), y0f = floorf(py), l0f = floorf(pl);
    float wx = px - x0f, wy = py - y0f, wl = pl - l0f;

    int ix0 = clampi((int)x0f, 0, RES - 1);
    int ix1 = ix0 + 1 > RES - 1 ? RES - 1 : ix0 + 1;
    int iy0 = clampi((int)y0f, 0, RES - 1);
    int iy1 = iy0 + 1 > RES - 1 ? RES - 1 : iy0 + 1;
    int il0 = clampi((int)l0f, 0, RES - 1);
    int il1 = il0 + 1 > RES - 1 ? RES - 1 : il0 + 1;

    unsigned cbase = c4 * 4u;
    const __half* pb = pt + (size_t)p * RES2 * NC;
    h4 v00 = *reinterpret_cast<const h4*>(pb + ((unsigned)iy0 * RES + (unsigned)ix0) * NC + cbase);
    h4 v01 = *reinterpret_cast<const h4*>(pb + ((unsigned)iy0 * RES + (unsigned)ix1) * NC + cbase);
    h4 v10 = *reinterpret_cast<const h4*>(pb + ((unsigned)iy1 * RES + (unsigned)ix0) * NC + cbase);
    h4 v11 = *reinterpret_cast<const h4*>(pb + ((unsigned)iy1 * RES + (unsigned)ix1) * NC + cbase);

    float2 f00a = __half22float2(v00.h[0]), f00b = __half22float2(v00.h[1]);
    float2 f01a = __half22float2(v01.h[0]), f01b = __half22float2(v01.h[1]);
    float2 f10a = __half22float2(v10.h[0]), f10b = __half22float2(v10.h[1]);
    float2 f11a = __half22float2(v11.h[0]), f11b = __half22float2(v11.h[1]);

    float w00 = (1.0f - wx) * (1.0f - wy);
    float w01 = wx * (1.0f - wy);
    float w10 = (1.0f - wx) * wy;
    float w11 = wx * wy;

    f32x4 plane_v;
    plane_v.x = f00a.x * w00 + f01a.x * w01 + f10a.x * w10 + f11a.x * w11;
    plane_v.y = f00a.y * w00 + f01a.y * w01 + f10a.y * w10 + f11a.y * w11;
    plane_v.z = f00b.x * w00 + f01b.x * w01 + f10b.x * w10 + f11b.x * w11;
    plane_v.w = f00b.y * w00 + f01b.y * w01 + f10b.y * w10 + f11b.y * w11;

    const __half* lb = lt + (size_t)p * RES * NC + cbase;
    h4 vl0 = *reinterpret_cast<const h4*>(lb + (size_t)il0 * NC);
    h4 vl1 = *reinterpret_cast<const h4*>(lb + (size_t)il1 * NC);
    float2 l0a = __half22float2(vl0.h[0]), l0b = __half22float2(vl0.h[1]);
    float2 l1a = __half22float2(vl1.h[0]), l1b = __half22float2(vl1.h[1]);

    float wl0 = 1.0f - wl;
    f32x4 line_v;
    line_v.x = l0a.x * wl0 + l1a.x * wl;
    line_v.y = l0a.y * wl0 + l1a.y * wl;
    line_v.z = l0b.x * wl0 + l1b.x * wl;
    line_v.w = l0b.y * wl0 + l1b.y * wl;

    f32x4 rr = plane_v * line_v;
    __builtin_nontemporal_store(rr, reinterpret_cast<f32x4*>(out + (size_t)n * 144u + (size_t)q * 4u));
}

// last-resort fallback: gather from original channel-major layout
__global__ __launch_bounds__(256) void encode_fallback_kernel(const float* __restrict__ x,
                                                              const float* __restrict__ plane,
                                                              const float* __restrict__ line,
                                                              float* __restrict__ out,
                                                              unsigned N) {
    unsigned gid = blockIdx.x * 256u + threadIdx.x;
    if (gid >= N * 36u) return;
    unsigned n  = gid / 36u;
    unsigned q  = gid - n * 36u;
    unsigned p  = q / 12u;
    unsigned c4 = q - p * 12u;

    float xv0 = x[3u * n + 0u];
    float xv1 = x[3u * n + 1u];
    float xv2 = x[3u * n + 2u];
    float gxv = (p == 2u) ? xv1 : xv0;
    float gyv = (p == 0u) ? xv1 : xv2;
    float glv = (p == 0u) ? xv2 : ((p == 1u) ? xv1 : xv0);

    float gxs = 2.0f * gxv - 1.0f;
    float gys = 2.0f * gyv - 1.0f;
    float gls = 2.0f * glv - 1.0f;
    float px = (gxs + 1.0f) * 0.5f * (float)(RES - 1);
    float py = (gys + 1.0f) * 0.5f * (float)(RES - 1);
    float pl = (gls + 1.0f) * 0.5f * (float)(RES - 1);

    float x0f = floorf(px), y0f = floorf(py), l0f = floorf(pl);
    float wx = px - x0f, wy = py - y0f, wl = pl - l0f;

    int ix0 = clampi((int)x0f, 0, RES - 1);
    int ix1 = ix0 + 1 > RES - 1 ? RES - 1 : ix0 + 1;
    int iy0 = clampi((int)y0f, 0, RES - 1);
    int iy1 = iy0 + 1 > RES - 1 ? RES - 1 : iy0 + 1;
    int il0 = clampi((int)l0f, 0, RES - 1);
    int il1 = il0 + 1 > RES - 1 ? RES - 1 : il0 + 1;

    float w00 = (1.0f - wx) * (1.0f - wy);
    float w01 = wx * (1.0f - wy);
    float w10 = (1.0f - wx) * wy;
    float w11 = wx * wy;
    float wl0 = 1.0f - wl;

    float4 r;
    float* rp = &r.x;
#pragma unroll
    for (int cc = 0; cc < 4; ++cc) {
        unsigned c = c4 * 4u + (unsigned)cc;
        const float* pp = plane + ((size_t)p * NC + c) * RES2;
        float f00 = pp[(size_t)iy0 * RES + ix0];
        float f01 = pp[(size_t)iy0 * RES + ix1];
        float f10 = pp[(size_t)iy1 * RES + ix0];
        float f11 = pp[(size_t)iy1 * RES + ix1];
        float pv = f00 * w00 + f01 * w01 + f10 * w10 + f11 * w11;
        const float* lp = line + ((size_t)p * NC + c) * RES;
        float lv = lp[il0] * wl0 + lp[il1] * wl;
        rp[cc] = pv * lv;
    }
    *reinterpret_cast<float4*>(out + (size_t)n * 144u + (size_t)q * 4u) = r;
}

extern "C" void kernel_launch(void* const* d_in, const int* in_sizes, int n_in,
                              void* d_out, int out_size, void* d_ws, size_t ws_size,
                              hipStream_t stream) {
    const float* x     = (const float*)d_in[0];
    const float* plane = (const float*)d_in[1];
    const float* line  = (const float*)d_in[2];
    float* out = (float*)d_out;
    unsigned N = (unsigned)(in_sizes[0] / 3);

    size_t plane_t_elems = (size_t)3 * RES2 * NC;
    size_t line_t_elems  = (size_t)3 * RES * NC;
    size_t sorted_bytes  = (size_t)N * 16u;
    size_t plane_bytes   = plane_t_elems * sizeof(__half);
    size_t line_bytes    = line_t_elems * sizeof(__half);
    size_t bins_bytes    = (size_t)NBINS * 4u;

    size_t need_mid  = plane_bytes + line_bytes;
    size_t need_full = sorted_bytes + plane_bytes + line_bytes + 2u * bins_bytes;

    unsigned pblocks = (N + 255u) / 256u;

    if (ws_size >= need_full) {
        char* base = (char*)d_ws;
        f32x4*   sorted  = (f32x4*)base;                      base += sorted_bytes;
        __half*  plane_t = (__half*)base;                     base += plane_bytes;
        __half*  line_t  = (__half*)base;                     base += line_bytes;
        unsigned* counts = (unsigned*)base;                   base += bins_bytes;
        unsigned* offs   = (unsigned*)base;

        unsigned total  = N * TPP;
        unsigned blocks = (total + 255u) / 256u;

        zero_bins_kernel<<<(NBINS + 255) / 256, 256, 0, stream>>>(counts);
        hist_kernel<<<pblocks, 256, 0, stream>>>(x, counts, N);
        tp_planes_kernel<<<(3u * RES2 + 255u) / 256u, 256, 0, stream>>>(plane, plane_t);
        tp_lines_kernel<<<(3u * RES + 255u) / 256u, 256, 0, stream>>>(line, line_t);
        scan_kernel<<<1, 1024, 0, stream>>>(counts, offs);
        scatter_kernel<<<pblocks, 256, 0, stream>>>(x, offs, sorted, N);
        encode_sorted_kernel<<<blocks, 256, 0, stream>>>(sorted, plane_t, line_t, out, N);
    } else if (ws_size >= need_mid) {
        __half* plane_t = (__half*)d_ws;
        __half* line_t  = plane_t + plane_t_elems;
        unsigned total  = N * 36u;
        unsigned blocks = (total + 255u) / 256u;
        tp_planes_kernel<<<(3u * RES2 + 255u) / 256u, 256, 0, stream>>>(plane, plane_t);
        tp_lines_kernel<<<(3u * RES + 255u) / 256u, 256, 0, stream>>>(line, line_t);
        encode_kernel<<<blocks, 256, 0, stream>>>(x, plane_t, line_t, out, N);
    } else {
        unsigned total  = N * 36u;
        unsigned blocks = (total + 255u) / 256u;
        encode_fallback_kernel<<<blocks, 256, 0, stream>>>(x, plane, line, out, N);
    }
}

// Round 5
// 281.751 us; speedup vs baseline: 1.5996x; 1.5996x over previous
//
#include <hip/hip_runtime.h>
#include <hip/hip_fp16.h>

#define RES 300
#define NC 48
#define RES2 (RES * RES)
#define NBINS 32768  // 32^3 Morton cells
#define TPP 12       // threads per point: 12 channel groups of 4; each thread does all 3 planes

typedef float f32x4 __attribute__((ext_vector_type(4)));
typedef unsigned int u32x4 __attribute__((ext_vector_type(4)));

struct alignas(8) h4 { __half2 h[2]; };

__device__ __forceinline__ int clampi(int v, int lo, int hi) {
    return v < lo ? lo : (v > hi ? hi : v);
}

// spread 5 bits: bit i -> bit 3i
__device__ __forceinline__ unsigned spread5(unsigned v) {
    v &= 31u;
    v = (v | (v << 8)) & 0x100Fu;
    v = (v | (v << 4)) & 0x10C3u;
    v = (v | (v << 2)) & 0x1249u;
    return v;
}

__device__ __forceinline__ unsigned morton_key(float a, float b, float c) {
    int ca = clampi((int)(a * 32.0f), 0, 31);
    int cb = clampi((int)(b * 32.0f), 0, 31);
    int cc = clampi((int)(c * 32.0f), 0, 31);
    return spread5((unsigned)ca) | (spread5((unsigned)cb) << 1) | (spread5((unsigned)cc) << 2);
}

// ---------------- table transpose (fp32 channel-major -> fp16 channel-last) ----------------

__global__ __launch_bounds__(256) void tp_planes_kernel(const float* __restrict__ in,
                                                        __half* __restrict__ out) {
    unsigned idx = blockIdx.x * 256u + threadIdx.x;
    if (idx >= 3u * RES2) return;
    unsigned p  = idx / RES2;
    unsigned yx = idx - p * RES2;
    const float* src = in + (size_t)p * NC * RES2 + yx;
    unsigned short v[NC];
#pragma unroll
    for (int c = 0; c < NC; ++c) {
        __half h = __float2half(src[(size_t)c * RES2]);
        v[c] = *reinterpret_cast<unsigned short*>(&h);
    }
    u32x4* dst = reinterpret_cast<u32x4*>(out + (size_t)idx * NC);
#pragma unroll
    for (int i = 0; i < 6; ++i) {
        u32x4 w;
        w.x = (unsigned)v[8 * i + 0] | ((unsigned)v[8 * i + 1] << 16);
        w.y = (unsigned)v[8 * i + 2] | ((unsigned)v[8 * i + 3] << 16);
        w.z = (unsigned)v[8 * i + 4] | ((unsigned)v[8 * i + 5] << 16);
        w.w = (unsigned)v[8 * i + 6] | ((unsigned)v[8 * i + 7] << 16);
        dst[i] = w;
    }
}

__global__ __launch_bounds__(256) void tp_lines_kernel(const float* __restrict__ in,
                                                       __half* __restrict__ out) {
    unsigned idx = blockIdx.x * 256u + threadIdx.x;
    if (idx >= 3u * RES) return;
    unsigned p = idx / RES;
    unsigned y = idx - p * RES;
#pragma unroll
    for (int c = 0; c < NC; ++c)
        out[(size_t)idx * NC + c] = __float2half(in[((size_t)p * NC + c) * RES + y]);
}

// ---------------- Morton counting sort ----------------

__global__ __launch_bounds__(256) void zero_bins_kernel(unsigned* __restrict__ counts) {
    unsigned i = blockIdx.x * 256u + threadIdx.x;
    if (i < NBINS) counts[i] = 0u;
}

__global__ __launch_bounds__(256) void hist_kernel(const float* __restrict__ x,
                                                   unsigned* __restrict__ counts,
                                                   unsigned N) {
    unsigned i = blockIdx.x * 256u + threadIdx.x;
    if (i >= N) return;
    unsigned k = morton_key(x[3u * i], x[3u * i + 1u], x[3u * i + 2u]);
    atomicAdd(&counts[k], 1u);
}

// one block, 1024 threads; exclusive scan of NBINS counts -> offs
__global__ __launch_bounds__(1024) void scan_kernel(const unsigned* __restrict__ counts,
                                                    unsigned* __restrict__ offs) {
    __shared__ unsigned part[1024];
    int t = threadIdx.x;
    unsigned local[NBINS / 1024];
    unsigned s = 0;
#pragma unroll
    for (int j = 0; j < NBINS / 1024; ++j) {
        local[j] = counts[t * (NBINS / 1024) + j];
        s += local[j];
    }
    part[t] = s;
    __syncthreads();
    for (int d = 1; d < 1024; d <<= 1) {
        unsigned v = (t >= d) ? part[t - d] : 0u;
        __syncthreads();
        part[t] += v;
        __syncthreads();
    }
    unsigned run = (t == 0) ? 0u : part[t - 1];
#pragma unroll
    for (int j = 0; j < NBINS / 1024; ++j) {
        offs[t * (NBINS / 1024) + j] = run;
        run += local[j];
    }
}

// scatter points into Morton order; offs is consumed (becomes end offsets)
__global__ __launch_bounds__(256) void scatter_kernel(const float* __restrict__ x,
                                                      unsigned* __restrict__ offs,
                                                      f32x4* __restrict__ sorted,
                                                      unsigned N) {
    unsigned i = blockIdx.x * 256u + threadIdx.x;
    if (i >= N) return;
    float a = x[3u * i], b = x[3u * i + 1u], c = x[3u * i + 2u];
    unsigned k = morton_key(a, b, c);
    unsigned pos = atomicAdd(&offs[k], 1u);
    f32x4 v;
    v.x = a; v.y = b; v.z = c; v.w = __uint_as_float(i);
    sorted[pos] = v;
}

// ---------------- encode (sorted, 12 threads/pt, all 3 planes per thread) ----------------

__global__ __launch_bounds__(256) void encode_sorted_kernel(const f32x4* __restrict__ sorted,
                                                            const __half* __restrict__ pt,  // (3,RES,RES,NC)
                                                            const __half* __restrict__ lt,  // (3,RES,NC)
                                                            float* __restrict__ out,
                                                            unsigned N) {
    // bijective XCD chunking: each XCD gets a contiguous chunk of the
    // Morton-sorted point range -> per-XCD L2 working set ~1 octant of the table.
    unsigned nwg  = gridDim.x;
    unsigned orig = blockIdx.x;
    unsigned xcd = orig & 7u, j = orig >> 3u;
    unsigned qq = nwg >> 3u, r = nwg & 7u;
    unsigned bid = (xcd < r ? xcd * (qq + 1u) : r * (qq + 1u) + (xcd - r) * qq) + j;

    unsigned gid = bid * 256u + threadIdx.x;
    if (gid >= N * TPP) return;
    unsigned s  = gid / TPP;
    unsigned c4 = gid - s * TPP;

    f32x4 pv4 = sorted[s];
    unsigned n = __float_as_uint(pv4.w);
    float xs0 = pv4.x, xs1 = pv4.y, xs2 = pv4.z;

    // per-plane coordinate selection:
    // p=0: gx=xs0 gy=xs1 gl=xs2 ; p=1: gx=xs0 gy=xs2 gl=xs1 ; p=2: gx=xs1 gy=xs2 gl=xs0
    unsigned cbase = c4 * 4u;

    h4 c00_0, c01_0, c10_0, c11_0, L0_0, L1_0;
    h4 c00_1, c01_1, c10_1, c11_1, L0_1, L1_1;
    h4 c00_2, c01_2, c10_2, c11_2, L0_2, L1_2;
    float w00_[3], w01_[3], w10_[3], w11_[3], wl_[3];

#pragma unroll
    for (int p = 0; p < 3; ++p) {
        float gxv = (p == 2) ? xs1 : xs0;
        float gyv = (p == 0) ? xs1 : xs2;
        float glv = (p == 0) ? xs2 : ((p == 1) ? xs1 : xs0);

        // mirror reference fp32 arithmetic
        float gxs = 2.0f * gxv - 1.0f;
        float gys = 2.0f * gyv - 1.0f;
        float gls = 2.0f * glv - 1.0f;
        float px = (gxs + 1.0f) * 0.5f * (float)(RES - 1);
        float py = (gys + 1.0f) * 0.5f * (float)(RES - 1);
        float pl = (gls + 1.0f) * 0.5f * (float)(RES - 1);

        float x0f = floorf(px), y0f = floorf(py), l0f = floorf(pl);
        float wx = px - x0f, wy = py - y0f, wl = pl - l0f;

        int ix0 = clampi((int)x0f, 0, RES - 1);
        int ix1 = ix0 + 1 > RES - 1 ? RES - 1 : ix0 + 1;
        int iy0 = clampi((int)y0f, 0, RES - 1);
        int iy1 = iy0 + 1 > RES - 1 ? RES - 1 : iy0 + 1;
        int il0 = clampi((int)l0f, 0, RES - 1);
        int il1 = il0 + 1 > RES - 1 ? RES - 1 : il0 + 1;

        w00_[p] = (1.0f - wx) * (1.0f - wy);
        w01_[p] = wx * (1.0f - wy);
        w10_[p] = (1.0f - wx) * wy;
        w11_[p] = wx * wy;
        wl_[p]  = wl;

        const __half* pb = pt + (size_t)p * RES2 * NC;
        const __half* lb = lt + (size_t)p * RES * NC + cbase;
        unsigned o00 = ((unsigned)iy0 * RES + (unsigned)ix0) * NC + cbase;
        unsigned o01 = ((unsigned)iy0 * RES + (unsigned)ix1) * NC + cbase;
        unsigned o10 = ((unsigned)iy1 * RES + (unsigned)ix0) * NC + cbase;
        unsigned o11 = ((unsigned)iy1 * RES + (unsigned)ix1) * NC + cbase;

        h4 a = *reinterpret_cast<const h4*>(pb + o00);
        h4 b = *reinterpret_cast<const h4*>(pb + o01);
        h4 c = *reinterpret_cast<const h4*>(pb + o10);
        h4 d = *reinterpret_cast<const h4*>(pb + o11);
        h4 e = *reinterpret_cast<const h4*>(lb + (size_t)il0 * NC);
        h4 f = *reinterpret_cast<const h4*>(lb + (size_t)il1 * NC);
        if (p == 0) { c00_0 = a; c01_0 = b; c10_0 = c; c11_0 = d; L0_0 = e; L1_0 = f; }
        if (p == 1) { c00_1 = a; c01_1 = b; c10_1 = c; c11_1 = d; L0_1 = e; L1_1 = f; }
        if (p == 2) { c00_2 = a; c01_2 = b; c10_2 = c; c11_2 = d; L0_2 = e; L1_2 = f; }
    }

    float* ob = out + (size_t)n * 144u + cbase;

#pragma unroll
    for (int p = 0; p < 3; ++p) {
        h4 v00 = (p == 0) ? c00_0 : (p == 1) ? c00_1 : c00_2;
        h4 v01 = (p == 0) ? c01_0 : (p == 1) ? c01_1 : c01_2;
        h4 v10 = (p == 0) ? c10_0 : (p == 1) ? c10_1 : c10_2;
        h4 v11 = (p == 0) ? c11_0 : (p == 1) ? c11_1 : c11_2;
        h4 vl0 = (p == 0) ? L0_0  : (p == 1) ? L0_1  : L0_2;
        h4 vl1 = (p == 0) ? L1_0  : (p == 1) ? L1_1  : L1_2;

        float2 f00a = __half22float2(v00.h[0]), f00b = __half22float2(v00.h[1]);
        float2 f01a = __half22float2(v01.h[0]), f01b = __half22float2(v01.h[1]);
        float2 f10a = __half22float2(v10.h[0]), f10b = __half22float2(v10.h[1]);
        float2 f11a = __half22float2(v11.h[0]), f11b = __half22float2(v11.h[1]);
        float2 l0a  = __half22float2(vl0.h[0]), l0b  = __half22float2(vl0.h[1]);
        float2 l1a  = __half22float2(vl1.h[0]), l1b  = __half22float2(vl1.h[1]);

        float w00 = w00_[p], w01 = w01_[p], w10 = w10_[p], w11 = w11_[p];
        float wl = wl_[p], wl0 = 1.0f - wl;

        f32x4 plane_v;
        plane_v.x = f00a.x * w00 + f01a.x * w01 + f10a.x * w10 + f11a.x * w11;
        plane_v.y = f00a.y * w00 + f01a.y * w01 + f10a.y * w10 + f11a.y * w11;
        plane_v.z = f00b.x * w00 + f01b.x * w01 + f10b.x * w10 + f11b.x * w11;
        plane_v.w = f00b.y * w00 + f01b.y * w01 + f10b.y * w10 + f11b.y * w11;

        f32x4 line_v;
        line_v.x = l0a.x * wl0 + l1a.x * wl;
        line_v.y = l0a.y * wl0 + l1a.y * wl;
        line_v.z = l0b.x * wl0 + l1b.x * wl;
        line_v.w = l0b.y * wl0 + l1b.y * wl;

        f32x4 rr = plane_v * line_v;
        // dense per-instruction store: lanes c4=0..11 cover 192B contiguous per plane
        __builtin_nontemporal_store(rr, reinterpret_cast<f32x4*>(ob + p * 48));
    }
}

// ---------------- unsorted encode (fallback when ws fits only tables) ----------------

__global__ __launch_bounds__(256) void encode_kernel(const float* __restrict__ x,
                                                     const __half* __restrict__ pt,
                                                     const __half* __restrict__ lt,
                                                     float* __restrict__ out,
                                                     unsigned N) {
    unsigned gid = blockIdx.x * 256u + threadIdx.x;
    if (gid >= N * 36u) return;
    unsigned n  = gid / 36u;
    unsigned q  = gid - n * 36u;
    unsigned p  = q / 12u;
    unsigned c4 = q - p * 12u;

    float xv0 = x[3u * n + 0u];
    float xv1 = x[3u * n + 1u];
    float xv2 = x[3u * n + 2u];
    float gxv = (p == 2u) ? xv1 : xv0;
    float gyv = (p == 0u) ? xv1 : xv2;
    float glv = (p == 0u) ? xv2 : ((p == 1u) ? xv1 : xv0);

    float gxs = 2.0f * gxv - 1.0f;
    float gys = 2.0f * gyv - 1.0f;
    float gls = 2.0f * glv - 1.0f;
    float px = (gxs + 1.0f) * 0.5f * (float)(RES - 1);
    float py = (gys + 1.0f) * 0.5f * (float)(RES - 1);
    float pl = (gls + 1.0f) * 0.5f * (float)(RES - 1);

    float x0f = floorf(px), y0f = floorf(py), l0f = floorf(pl);
    float wx = px - x0f, wy = py - y0f, wl = pl - l0f;

    int ix0 = clampi((int)x0f, 0, RES - 1);
    int ix1 = ix0 + 1 > RES - 1 ? RES - 1 : ix0 + 1;
    int iy0 = clampi((int)y0f, 0, RES - 1);
    int iy1 = iy0 + 1 > RES - 1 ? RES - 1 : iy0 + 1;
    int il0 = clampi((int)l0f, 0, RES - 1);
    int il1 = il0 + 1 > RES - 1 ? RES - 1 : il0 + 1;

    unsigned cbase = c4 * 4u;
    const __half* pb = pt + (size_t)p * RES2 * NC;
    h4 v00 = *reinterpret_cast<const h4*>(pb + ((unsigned)iy0 * RES + (unsigned)ix0) * NC + cbase);
    h4 v01 = *reinterpret_cast<const h4*>(pb + ((unsigned)iy0 * RES + (unsigned)ix1) * NC + cbase);
    h4 v10 = *reinterpret_cast<const h4*>(pb + ((unsigned)iy1 * RES + (unsigned)ix0) * NC + cbase);
    h4 v11 = *reinterpret_cast<const h4*>(pb + ((unsigned)iy1 * RES + (unsigned)ix1) * NC + cbase);

    float2 f00a = __half22float2(v00.h[0]), f00b = __half22float2(v00.h[1]);
    float2 f01a = __half22float2(v01.h[0]), f01b = __half22float2(v01.h[1]);
    float2 f10a = __half22float2(v10.h[0]), f10b = __half22float2(v10.h[1]);
    float2 f11a = __half22float2(v11.h[0]), f11b = __half22float2(v11.h[1]);

    float w00 = (1.0f - wx) * (1.0f - wy);
    float w01 = wx * (1.0f - wy);
    float w10 = (1.0f - wx) * wy;
    float w11 = wx * wy;

    f32x4 plane_v;
    plane_v.x = f00a.x * w00 + f01a.x * w01 + f10a.x * w10 + f11a.x * w11;
    plane_v.y = f00a.y * w00 + f01a.y * w01 + f10a.y * w10 + f11a.y * w11;
    plane_v.z = f00b.x * w00 + f01b.x * w01 + f10b.x * w10 + f11b.x * w11;
    plane_v.w = f00b.y * w00 + f01b.y * w01 + f10b.y * w10 + f11b.y * w11;

    const __half* lb = lt + (size_t)p * RES * NC + cbase;
    h4 vl0 = *reinterpret_cast<const h4*>(lb + (size_t)il0 * NC);
    h4 vl1 = *reinterpret_cast<const h4*>(lb + (size_t)il1 * NC);
    float2 l0a = __half22float2(vl0.h[0]), l0b = __half22float2(vl0.h[1]);
    float2 l1a = __half22float2(vl1.h[0]), l1b = __half22float2(vl1.h[1]);

    float wl0 = 1.0f - wl;
    f32x4 line_v;
    line_v.x = l0a.x * wl0 + l1a.x * wl;
    line_v.y = l0a.y * wl0 + l1a.y * wl;
    line_v.z = l0b.x * wl0 + l1b.x * wl;
    line_v.w = l0b.y * wl0 + l1b.y * wl;

    f32x4 rr = plane_v * line_v;
    __builtin_nontemporal_store(rr, reinterpret_cast<f32x4*>(out + (size_t)n * 144u + (size_t)q * 4u));
}

// last-resort fallback: gather from original channel-major layout
__global__ __launch_bounds__(256) void encode_fallback_kernel(const float* __restrict__ x,
                                                              const float* __restrict__ plane,
                                                              const float* __restrict__ line,
                                                              float* __restrict__ out,
                                                              unsigned N) {
    unsigned gid = blockIdx.x * 256u + threadIdx.x;
    if (gid >= N * 36u) return;
    unsigned n  = gid / 36u;
    unsigned q  = gid - n * 36u;
    unsigned p  = q / 12u;
    unsigned c4 = q - p * 12u;

    float xv0 = x[3u * n + 0u];
    float xv1 = x[3u * n + 1u];
    float xv2 = x[3u * n + 2u];
    float gxv = (p == 2u) ? xv1 : xv0;
    float gyv = (p == 0u) ? xv1 : xv2;
    float glv = (p == 0u) ? xv2 : ((p == 1u) ? xv1 : xv0);

    float gxs = 2.0f * gxv - 1.0f;
    float gys = 2.0f * gyv - 1.0f;
    float gls = 2.0f * glv - 1.0f;
    float px = (gxs + 1.0f) * 0.5f * (float)(RES - 1);
    float py = (gys + 1.0f) * 0.5f * (float)(RES - 1);
    float pl = (gls + 1.0f) * 0.5f * (float)(RES - 1);

    float x0f = floorf(px), y0f = floorf(py), l0f = floorf(pl);
    float wx = px - x0f, wy = py - y0f, wl = pl - l0f;

    int ix0 = clampi((int)x0f, 0, RES - 1);
    int ix1 = ix0 + 1 > RES - 1 ? RES - 1 : ix0 + 1;
    int iy0 = clampi((int)y0f, 0, RES - 1);
    int iy1 = iy0 + 1 > RES - 1 ? RES - 1 : iy0 + 1;
    int il0 = clampi((int)l0f, 0, RES - 1);
    int il1 = il0 + 1 > RES - 1 ? RES - 1 : il0 + 1;

    float w00 = (1.0f - wx) * (1.0f - wy);
    float w01 = wx * (1.0f - wy);
    float w10 = (1.0f - wx) * wy;
    float w11 = wx * wy;
    float wl0 = 1.0f - wl;

    float4 r;
    float* rp = &r.x;
#pragma unroll
    for (int cc = 0; cc < 4; ++cc) {
        unsigned c = c4 * 4u + (unsigned)cc;
        const float* pp = plane + ((size_t)p * NC + c) * RES2;
        float f00 = pp[(size_t)iy0 * RES + ix0];
        float f01 = pp[(size_t)iy0 * RES + ix1];
        float f10 = pp[(size_t)iy1 * RES + ix0];
        float f11 = pp[(size_t)iy1 * RES + ix1];
        float pv = f00 * w00 + f01 * w01 + f10 * w10 + f11 * w11;
        const float* lp = line + ((size_t)p * NC + c) * RES;
        float lv = lp[il0] * wl0 + lp[il1] * wl;
        rp[cc] = pv * lv;
    }
    *reinterpret_cast<float4*>(out + (size_t)n * 144u + (size_t)q * 4u) = r;
}

extern "C" void kernel_launch(void* const* d_in, const int* in_sizes, int n_in,
                              void* d_out, int out_size, void* d_ws, size_t ws_size,
                              hipStream_t stream) {
    const float* x     = (const float*)d_in[0];
    const float* plane = (const float*)d_in[1];
    const float* line  = (const float*)d_in[2];
    float* out = (float*)d_out;
    unsigned N = (unsigned)(in_sizes[0] / 3);

    size_t plane_t_elems = (size_t)3 * RES2 * NC;
    size_t line_t_elems  = (size_t)3 * RES * NC;
    size_t sorted_bytes  = (size_t)N * 16u;
    size_t plane_bytes   = plane_t_elems * sizeof(__half);
    size_t line_bytes    = line_t_elems * sizeof(__half);
    size_t bins_bytes    = (size_t)NBINS * 4u;

    size_t need_mid  = plane_bytes + line_bytes;
    size_t need_full = sorted_bytes + plane_bytes + line_bytes + 2u * bins_bytes;

    unsigned pblocks = (N + 255u) / 256u;

    if (ws_size >= need_full) {
        char* base = (char*)d_ws;
        f32x4*   sorted  = (f32x4*)base;                      base += sorted_bytes;
        __half*  plane_t = (__half*)base;                     base += plane_bytes;
        __half*  line_t  = (__half*)base;                     base += line_bytes;
        unsigned* counts = (unsigned*)base;                   base += bins_bytes;
        unsigned* offs   = (unsigned*)base;

        unsigned total  = N * TPP;
        unsigned blocks = (total + 255u) / 256u;

        zero_bins_kernel<<<(NBINS + 255) / 256, 256, 0, stream>>>(counts);
        hist_kernel<<<pblocks, 256, 0, stream>>>(x, counts, N);
        tp_planes_kernel<<<(3u * RES2 + 255u) / 256u, 256, 0, stream>>>(plane, plane_t);
        tp_lines_kernel<<<(3u * RES + 255u) / 256u, 256, 0, stream>>>(line, line_t);
        scan_kernel<<<1, 1024, 0, stream>>>(counts, offs);
        scatter_kernel<<<pblocks, 256, 0, stream>>>(x, offs, sorted, N);
        encode_sorted_kernel<<<blocks, 256, 0, stream>>>(sorted, plane_t, line_t, out, N);
    } else if (ws_size >= need_mid) {
        __half* plane_t = (__half*)d_ws;
        __half* line_t  = plane_t + plane_t_elems;
        unsigned total  = N * 36u;
        unsigned blocks = (total + 255u) / 256u;
        tp_planes_kernel<<<(3u * RES2 + 255u) / 256u, 256, 0, stream>>>(plane, plane_t);
        tp_lines_kernel<<<(3u * RES + 255u) / 256u, 256, 0, stream>>>(line, line_t);
        encode_kernel<<<blocks, 256, 0, stream>>>(x, plane_t, line_t, out, N);
    } else {
        unsigned total  = N * 36u;
        unsigned blocks = (total + 255u) / 256u;
        encode_fallback_kernel<<<blocks, 256, 0, stream>>>(x, plane, line, out, N);
    }
}

// Round 6
// 273.905 us; speedup vs baseline: 1.6454x; 1.0286x over previous
//
#include <hip/hip_runtime.h>
#include <hip/hip_fp16.h>

#define RES 300
#define NC 48
#define RES2 (RES * RES)
#define CELLS 64            // cells per axis
#define NBINS (CELLS*CELLS*CELLS)   // 262144 Morton cells
#define SCAN_T 1024
#define SCAN_BLK (NBINS / SCAN_T)   // 256
#define TPP 12              // threads per point: 12 channel groups of 4; each thread does all 3 planes

typedef float f32x4 __attribute__((ext_vector_type(4)));
typedef unsigned int u32x4 __attribute__((ext_vector_type(4)));

struct alignas(8) h4 { __half2 h[2]; };

__device__ __forceinline__ int clampi(int v, int lo, int hi) {
    return v < lo ? lo : (v > hi ? hi : v);
}

// spread up to 10 bits: bit i -> bit 3i
__device__ __forceinline__ unsigned spread3(unsigned v) {
    v = (v | (v << 16)) & 0x030000FFu;
    v = (v | (v << 8))  & 0x0300F00Fu;
    v = (v | (v << 4))  & 0x030C30C3u;
    v = (v | (v << 2))  & 0x09249249u;
    return v;
}

__device__ __forceinline__ unsigned morton_key(float a, float b, float c) {
    unsigned ca = (unsigned)clampi((int)(a * (float)CELLS), 0, CELLS - 1);
    unsigned cb = (unsigned)clampi((int)(b * (float)CELLS), 0, CELLS - 1);
    unsigned cc = (unsigned)clampi((int)(c * (float)CELLS), 0, CELLS - 1);
    return spread3(ca) | (spread3(cb) << 1) | (spread3(cc) << 2);
}

// ---------------- table transpose (fp32 channel-major -> fp16 channel-last), fused ----------------

__global__ __launch_bounds__(256) void tp_tables_kernel(const float* __restrict__ pin,
                                                        const float* __restrict__ lin,
                                                        __half* __restrict__ pout,
                                                        __half* __restrict__ lout) {
    unsigned idx = blockIdx.x * 256u + threadIdx.x;
    if (idx < 3u * RES2) {
        unsigned p  = idx / RES2;
        unsigned yx = idx - p * RES2;
        const float* src = pin + (size_t)p * NC * RES2 + yx;
        unsigned short v[NC];
#pragma unroll
        for (int c = 0; c < NC; ++c) {
            __half h = __float2half(src[(size_t)c * RES2]);
            v[c] = *reinterpret_cast<unsigned short*>(&h);
        }
        u32x4* dst = reinterpret_cast<u32x4*>(pout + (size_t)idx * NC);
#pragma unroll
        for (int i = 0; i < 6; ++i) {
            u32x4 w;
            w.x = (unsigned)v[8 * i + 0] | ((unsigned)v[8 * i + 1] << 16);
            w.y = (unsigned)v[8 * i + 2] | ((unsigned)v[8 * i + 3] << 16);
            w.z = (unsigned)v[8 * i + 4] | ((unsigned)v[8 * i + 5] << 16);
            w.w = (unsigned)v[8 * i + 6] | ((unsigned)v[8 * i + 7] << 16);
            dst[i] = w;
        }
    } else {
        unsigned li = idx - 3u * RES2;
        if (li >= 3u * RES) return;
        unsigned p = li / RES;
        unsigned y = li - p * RES;
#pragma unroll
        for (int c = 0; c < NC; ++c)
            lout[(size_t)li * NC + c] = __float2half(lin[((size_t)p * NC + c) * RES + y]);
    }
}

// ---------------- Morton counting sort ----------------

__global__ __launch_bounds__(256) void zero_bins_kernel(unsigned* __restrict__ counts) {
    unsigned i = blockIdx.x * 256u + threadIdx.x;
    if (i < NBINS) counts[i] = 0u;
}

__global__ __launch_bounds__(256) void hist_kernel(const float* __restrict__ x,
                                                   unsigned* __restrict__ counts,
                                                   unsigned N) {
    unsigned i = blockIdx.x * 256u + threadIdx.x;
    if (i >= N) return;
    unsigned k = morton_key(x[3u * i], x[3u * i + 1u], x[3u * i + 2u]);
    atomicAdd(&counts[k], 1u);
}

// stage 1: per-block (1024 bins) exclusive scan + block sum
__global__ __launch_bounds__(SCAN_T) void scan1_kernel(const unsigned* __restrict__ counts,
                                                       unsigned* __restrict__ pre,
                                                       unsigned* __restrict__ bsum) {
    __shared__ unsigned part[SCAN_T];
    unsigned b = blockIdx.x * SCAN_T + threadIdx.x;
    int t = threadIdx.x;
    unsigned c = counts[b];
    part[t] = c;
    __syncthreads();
    for (int d = 1; d < SCAN_T; d <<= 1) {
        unsigned v = (t >= d) ? part[t - d] : 0u;
        __syncthreads();
        part[t] += v;
        __syncthreads();
    }
    pre[b] = part[t] - c;                    // exclusive within block
    if (t == SCAN_T - 1) bsum[blockIdx.x] = part[t];
}

// stage 2: one block, exclusive scan of SCAN_BLK block sums
__global__ __launch_bounds__(SCAN_BLK) void scan2_kernel(unsigned* __restrict__ bsum,
                                                         unsigned* __restrict__ boff) {
    __shared__ unsigned part[SCAN_BLK];
    int t = threadIdx.x;
    unsigned c = bsum[t];
    part[t] = c;
    __syncthreads();
    for (int d = 1; d < SCAN_BLK; d <<= 1) {
        unsigned v = (t >= d) ? part[t - d] : 0u;
        __syncthreads();
        part[t] += v;
        __syncthreads();
    }
    boff[t] = part[t] - c;
}

// stage 3: offs = pre + boff[blk]
__global__ __launch_bounds__(SCAN_T) void scan3_kernel(const unsigned* __restrict__ pre,
                                                       const unsigned* __restrict__ boff,
                                                       unsigned* __restrict__ offs) {
    unsigned b = blockIdx.x * SCAN_T + threadIdx.x;
    offs[b] = pre[b] + boff[blockIdx.x];
}

// scatter points into Morton order; offs is consumed (becomes end offsets)
__global__ __launch_bounds__(256) void scatter_kernel(const float* __restrict__ x,
                                                      unsigned* __restrict__ offs,
                                                      f32x4* __restrict__ sorted,
                                                      unsigned N) {
    unsigned i = blockIdx.x * 256u + threadIdx.x;
    if (i >= N) return;
    float a = x[3u * i], b = x[3u * i + 1u], c = x[3u * i + 2u];
    unsigned k = morton_key(a, b, c);
    unsigned pos = atomicAdd(&offs[k], 1u);
    f32x4 v;
    v.x = a; v.y = b; v.z = c; v.w = __uint_as_float(i);
    sorted[pos] = v;
}

// ---------------- encode (sorted, 12 threads/pt, all 3 planes per thread) ----------------

__global__ __launch_bounds__(256) void encode_sorted_kernel(const f32x4* __restrict__ sorted,
                                                            const __half* __restrict__ pt,  // (3,RES,RES,NC)
                                                            const __half* __restrict__ lt,  // (3,RES,NC)
                                                            float* __restrict__ out,
                                                            unsigned N) {
    // bijective XCD chunking: each XCD gets a contiguous chunk of the
    // Morton-sorted point range -> per-XCD L2 working set ~1 octant of the table.
    unsigned nwg  = gridDim.x;
    unsigned orig = blockIdx.x;
    unsigned xcd = orig & 7u, j = orig >> 3u;
    unsigned qq = nwg >> 3u, r = nwg & 7u;
    unsigned bid = (xcd < r ? xcd * (qq + 1u) : r * (qq + 1u) + (xcd - r) * qq) + j;

    unsigned gid = bid * 256u + threadIdx.x;
    if (gid >= N * TPP) return;
    unsigned s  = gid / TPP;
    unsigned c4 = gid - s * TPP;

    f32x4 pv4 = sorted[s];
    unsigned n = __float_as_uint(pv4.w);
    float xs0 = pv4.x, xs1 = pv4.y, xs2 = pv4.z;

    unsigned cbase = c4 * 4u;

    h4 c00_0, c01_0, c10_0, c11_0, L0_0, L1_0;
    h4 c00_1, c01_1, c10_1, c11_1, L0_1, L1_1;
    h4 c00_2, c01_2, c10_2, c11_2, L0_2, L1_2;
    float w00_[3], w01_[3], w10_[3], w11_[3], wl_[3];

#pragma unroll
    for (int p = 0; p < 3; ++p) {
        float gxv = (p == 2) ? xs1 : xs0;
        float gyv = (p == 0) ? xs1 : xs2;
        float glv = (p == 0) ? xs2 : ((p == 1) ? xs1 : xs0);

        // mirror reference fp32 arithmetic
        float gxs = 2.0f * gxv - 1.0f;
        float gys = 2.0f * gyv - 1.0f;
        float gls = 2.0f * glv - 1.0f;
        float px = (gxs + 1.0f) * 0.5f * (float)(RES - 1);
        float py = (gys + 1.0f) * 0.5f * (float)(RES - 1);
        float pl = (gls + 1.0f) * 0.5f * (float)(RES - 1);

        float x0f = floorf(px), y0f = floorf(py), l0f = floorf(pl);
        float wx = px - x0f, wy = py - y0f, wl = pl - l0f;

        int ix0 = clampi((int)x0f, 0, RES - 1);
        int ix1 = ix0 + 1 > RES - 1 ? RES - 1 : ix0 + 1;
        int iy0 = clampi((int)y0f, 0, RES - 1);
        int iy1 = iy0 + 1 > RES - 1 ? RES - 1 : iy0 + 1;
        int il0 = clampi((int)l0f, 0, RES - 1);
        int il1 = il0 + 1 > RES - 1 ? RES - 1 : il0 + 1;

        w00_[p] = (1.0f - wx) * (1.0f - wy);
        w01_[p] = wx * (1.0f - wy);
        w10_[p] = (1.0f - wx) * wy;
        w11_[p] = wx * wy;
        wl_[p]  = wl;

        const __half* pb = pt + (size_t)p * RES2 * NC;
        const __half* lb = lt + (size_t)p * RES * NC + cbase;
        unsigned o00 = ((unsigned)iy0 * RES + (unsigned)ix0) * NC + cbase;
        unsigned o01 = ((unsigned)iy0 * RES + (unsigned)ix1) * NC + cbase;
        unsigned o10 = ((unsigned)iy1 * RES + (unsigned)ix0) * NC + cbase;
        unsigned o11 = ((unsigned)iy1 * RES + (unsigned)ix1) * NC + cbase;

        h4 a = *reinterpret_cast<const h4*>(pb + o00);
        h4 b = *reinterpret_cast<const h4*>(pb + o01);
        h4 c = *reinterpret_cast<const h4*>(pb + o10);
        h4 d = *reinterpret_cast<const h4*>(pb + o11);
        h4 e = *reinterpret_cast<const h4*>(lb + (size_t)il0 * NC);
        h4 f = *reinterpret_cast<const h4*>(lb + (size_t)il1 * NC);
        if (p == 0) { c00_0 = a; c01_0 = b; c10_0 = c; c11_0 = d; L0_0 = e; L1_0 = f; }
        if (p == 1) { c00_1 = a; c01_1 = b; c10_1 = c; c11_1 = d; L0_1 = e; L1_1 = f; }
        if (p == 2) { c00_2 = a; c01_2 = b; c10_2 = c; c11_2 = d; L0_2 = e; L1_2 = f; }
    }

    float* ob = out + (size_t)n * 144u + cbase;

#pragma unroll
    for (int p = 0; p < 3; ++p) {
        h4 v00 = (p == 0) ? c00_0 : (p == 1) ? c00_1 : c00_2;
        h4 v01 = (p == 0) ? c01_0 : (p == 1) ? c01_1 : c01_2;
        h4 v10 = (p == 0) ? c10_0 : (p == 1) ? c10_1 : c10_2;
        h4 v11 = (p == 0) ? c11_0 : (p == 1) ? c11_1 : c11_2;
        h4 vl0 = (p == 0) ? L0_0  : (p == 1) ? L0_1  : L0_2;
        h4 vl1 = (p == 0) ? L1_0  : (p == 1) ? L1_1  : L1_2;

        float2 f00a = __half22float2(v00.h[0]), f00b = __half22float2(v00.h[1]);
        float2 f01a = __half22float2(v01.h[0]), f01b = __half22float2(v01.h[1]);
        float2 f10a = __half22float2(v10.h[0]), f10b = __half22float2(v10.h[1]);
        float2 f11a = __half22float2(v11.h[0]), f11b = __half22float2(v11.h[1]);
        float2 l0a  = __half22float2(vl0.h[0]), l0b  = __half22float2(vl0.h[1]);
        float2 l1a  = __half22float2(vl1.h[0]), l1b  = __half22float2(vl1.h[1]);

        float w00 = w00_[p], w01 = w01_[p], w10 = w10_[p], w11 = w11_[p];
        float wl = wl_[p], wl0 = 1.0f - wl;

        f32x4 plane_v;
        plane_v.x = f00a.x * w00 + f01a.x * w01 + f10a.x * w10 + f11a.x * w11;
        plane_v.y = f00a.y * w00 + f01a.y * w01 + f10a.y * w10 + f11a.y * w11;
        plane_v.z = f00b.x * w00 + f01b.x * w01 + f10b.x * w10 + f11b.x * w11;
        plane_v.w = f00b.y * w00 + f01b.y * w01 + f10b.y * w10 + f11b.y * w11;

        f32x4 line_v;
        line_v.x = l0a.x * wl0 + l1a.x * wl;
        line_v.y = l0a.y * wl0 + l1a.y * wl;
        line_v.z = l0b.x * wl0 + l1b.x * wl;
        line_v.w = l0b.y * wl0 + l1b.y * wl;

        f32x4 rr = plane_v * line_v;
        // dense per-instruction store: lanes c4=0..11 cover 192B contiguous per plane
        __builtin_nontemporal_store(rr, reinterpret_cast<f32x4*>(ob + p * 48));
    }
}

// ---------------- unsorted encode (fallback when ws fits only tables) ----------------

__global__ __launch_bounds__(256) void encode_kernel(const float* __restrict__ x,
                                                     const __half* __restrict__ pt,
                                                     const __half* __restrict__ lt,
                                                     float* __restrict__ out,
                                                     unsigned N) {
    unsigned gid = blockIdx.x * 256u + threadIdx.x;
    if (gid >= N * 36u) return;
    unsigned n  = gid / 36u;
    unsigned q  = gid - n * 36u;
    unsigned p  = q / 12u;
    unsigned c4 = q - p * 12u;

    float xv0 = x[3u * n + 0u];
    float xv1 = x[3u * n + 1u];
    float xv2 = x[3u * n + 2u];
    float gxv = (p == 2u) ? xv1 : xv0;
    float gyv = (p == 0u) ? xv1 : xv2;
    float glv = (p == 0u) ? xv2 : ((p == 1u) ? xv1 : xv0);

    float gxs = 2.0f * gxv - 1.0f;
    float gys = 2.0f * gyv - 1.0f;
    float gls = 2.0f * glv - 1.0f;
    float px = (gxs + 1.0f) * 0.5f * (float)(RES - 1);
    float py = (gys + 1.0f) * 0.5f * (float)(RES - 1);
    float pl = (gls + 1.0f) * 0.5f * (float)(RES - 1);

    float x0f = floorf(px), y0f = floorf(py), l0f = floorf(pl);
    float wx = px - x0f, wy = py - y0f, wl = pl - l0f;

    int ix0 = clampi((int)x0f, 0, RES - 1);
    int ix1 = ix0 + 1 > RES - 1 ? RES - 1 : ix0 + 1;
    int iy0 = clampi((int)y0f, 0, RES - 1);
    int iy1 = iy0 + 1 > RES - 1 ? RES - 1 : iy0 + 1;
    int il0 = clampi((int)l0f, 0, RES - 1);
    int il1 = il0 + 1 > RES - 1 ? RES - 1 : il0 + 1;

    unsigned cbase = c4 * 4u;
    const __half* pb = pt + (size_t)p * RES2 * NC;
    h4 v00 = *reinterpret_cast<const h4*>(pb + ((unsigned)iy0 * RES + (unsigned)ix0) * NC + cbase);
    h4 v01 = *reinterpret_cast<const h4*>(pb + ((unsigned)iy0 * RES + (unsigned)ix1) * NC + cbase);
    h4 v10 = *reinterpret_cast<const h4*>(pb + ((unsigned)iy1 * RES + (unsigned)ix0) * NC + cbase);
    h4 v11 = *reinterpret_cast<const h4*>(pb + ((unsigned)iy1 * RES + (unsigned)ix1) * NC + cbase);

    float2 f00a = __half22float2(v00.h[0]), f00b = __half22float2(v00.h[1]);
    float2 f01a = __half22float2(v01.h[0]), f01b = __half22float2(v01.h[1]);
    float2 f10a = __half22float2(v10.h[0]), f10b = __half22float2(v10.h[1]);
    float2 f11a = __half22float2(v11.h[0]), f11b = __half22float2(v11.h[1]);

    float w00 = (1.0f - wx) * (1.0f - wy);
    float w01 = wx * (1.0f - wy);
    float w10 = (1.0f - wx) * wy;
    float w11 = wx * wy;

    f32x4 plane_v;
    plane_v.x = f00a.x * w00 + f01a.x * w01 + f10a.x * w10 + f11a.x * w11;
    plane_v.y = f00a.y * w00 + f01a.y * w01 + f10a.y * w10 + f11a.y * w11;
    plane_v.z = f00b.x * w00 + f01b.x * w01 + f10b.x * w10 + f11b.x * w11;
    plane_v.w = f00b.y * w00 + f01b.y * w01 + f10b.y * w10 + f11b.y * w11;

    const __half* lb = lt + (size_t)p * RES * NC + cbase;
    h4 vl0 = *reinterpret_cast<const h4*>(lb + (size_t)il0 * NC);
    h4 vl1 = *reinterpret_cast<const h4*>(lb + (size_t)il1 * NC);
    float2 l0a = __half22float2(vl0.h[0]), l0b = __half22float2(vl0.h[1]);
    float2 l1a = __half22float2(vl1.h[0]), l1b = __half22float2(vl1.h[1]);

    float wl0 = 1.0f - wl;
    f32x4 line_v;
    line_v.x = l0a.x * wl0 + l1a.x * wl;
    line_v.y = l0a.y * wl0 + l1a.y * wl;
    line_v.z = l0b.x * wl0 + l1b.x * wl;
    line_v.w = l0b.y * wl0 + l1b.y * wl;

    f32x4 rr = plane_v * line_v;
    __builtin_nontemporal_store(rr, reinterpret_cast<f32x4*>(out + (size_t)n * 144u + (size_t)q * 4u));
}

// last-resort fallback: gather from original channel-major layout
__global__ __launch_bounds__(256) void encode_fallback_kernel(const float* __restrict__ x,
                                                              const float* __restrict__ plane,
                                                              const float* __restrict__ line,
                                                              float* __restrict__ out,
                                                              unsigned N) {
    unsigned gid = blockIdx.x * 256u + threadIdx.x;
    if (gid >= N * 36u) return;
    unsigned n  = gid / 36u;
    unsigned q  = gid - n * 36u;
    unsigned p  = q / 12u;
    unsigned c4 = q - p * 12u;

    float xv0 = x[3u * n + 0u];
    float xv1 = x[3u * n + 1u];
    float xv2 = x[3u * n + 2u];
    float gxv = (p == 2u) ? xv1 : xv0;
    float gyv = (p == 0u) ? xv1 : xv2;
    float glv = (p == 0u) ? xv2 : ((p == 1u) ? xv1 : xv0);

    float gxs = 2.0f * gxv - 1.0f;
    float gys = 2.0f * gyv - 1.0f;
    float gls = 2.0f * glv - 1.0f;
    float px = (gxs + 1.0f) * 0.5f * (float)(RES - 1);
    float py = (gys + 1.0f) * 0.5f * (float)(RES - 1);
    float pl = (gls + 1.0f) * 0.5f * (float)(RES - 1);

    float x0f = floorf(px), y0f = floorf(py), l0f = floorf(pl);
    float wx = px - x0f, wy = py - y0f, wl = pl - l0f;

    int ix0 = clampi((int)x0f, 0, RES - 1);
    int ix1 = ix0 + 1 > RES - 1 ? RES - 1 : ix0 + 1;
    int iy0 = clampi((int)y0f, 0, RES - 1);
    int iy1 = iy0 + 1 > RES - 1 ? RES - 1 : iy0 + 1;
    int il0 = clampi((int)l0f, 0, RES - 1);
    int il1 = il0 + 1 > RES - 1 ? RES - 1 : il0 + 1;

    float w00 = (1.0f - wx) * (1.0f - wy);
    float w01 = wx * (1.0f - wy);
    float w10 = (1.0f - wx) * wy;
    float w11 = wx * wy;
    float wl0 = 1.0f - wl;

    float4 r;
    float* rp = &r.x;
#pragma unroll
    for (int cc = 0; cc < 4; ++cc) {
        unsigned c = c4 * 4u + (unsigned)cc;
        const float* pp = plane + ((size_t)p * NC + c) * RES2;
        float f00 = pp[(size_t)iy0 * RES + ix0];
        float f01 = pp[(size_t)iy0 * RES + ix1];
        float f10 = pp[(size_t)iy1 * RES + ix0];
        float f11 = pp[(size_t)iy1 * RES + ix1];
        float pv = f00 * w00 + f01 * w01 + f10 * w10 + f11 * w11;
        const float* lp = line + ((size_t)p * NC + c) * RES;
        float lv = lp[il0] * wl0 + lp[il1] * wl;
        rp[cc] = pv * lv;
    }
    *reinterpret_cast<float4*>(out + (size_t)n * 144u + (size_t)q * 4u) = r;
}

extern "C" void kernel_launch(void* const* d_in, const int* in_sizes, int n_in,
                              void* d_out, int out_size, void* d_ws, size_t ws_size,
                              hipStream_t stream) {
    const float* x     = (const float*)d_in[0];
    const float* plane = (const float*)d_in[1];
    const float* line  = (const float*)d_in[2];
    float* out = (float*)d_out;
    unsigned N = (unsigned)(in_sizes[0] / 3);

    size_t plane_t_elems = (size_t)3 * RES2 * NC;
    size_t line_t_elems  = (size_t)3 * RES * NC;
    size_t sorted_bytes  = (size_t)N * 16u;
    size_t plane_bytes   = plane_t_elems * sizeof(__half);
    size_t line_bytes    = line_t_elems * sizeof(__half);
    size_t bins_bytes    = (size_t)NBINS * 4u;
    size_t bsum_bytes    = (size_t)SCAN_BLK * 4u;

    size_t need_mid  = plane_bytes + line_bytes;
    size_t need_full = sorted_bytes + plane_bytes + line_bytes + 3u * bins_bytes + 2u * bsum_bytes;

    unsigned pblocks = (N + 255u) / 256u;
    unsigned tpblocks = (3u * RES2 + 3u * RES + 255u) / 256u;

    if (ws_size >= need_full) {
        char* base = (char*)d_ws;
        f32x4*   sorted  = (f32x4*)base;    base += sorted_bytes;
        __half*  plane_t = (__half*)base;   base += plane_bytes;
        __half*  line_t  = (__half*)base;   base += line_bytes;
        unsigned* counts = (unsigned*)base; base += bins_bytes;
        unsigned* pre    = (unsigned*)base; base += bins_bytes;
        unsigned* offs   = (unsigned*)base; base += bins_bytes;
        unsigned* bsum   = (unsigned*)base; base += bsum_bytes;
        unsigned* boff   = (unsigned*)base;

        unsigned total  = N * TPP;
        unsigned blocks = (total + 255u) / 256u;

        zero_bins_kernel<<<(NBINS + 255) / 256, 256, 0, stream>>>(counts);
        hist_kernel<<<pblocks, 256, 0, stream>>>(x, counts, N);
        tp_tables_kernel<<<tpblocks, 256, 0, stream>>>(plane, line, plane_t, line_t);
        scan1_kernel<<<SCAN_BLK, SCAN_T, 0, stream>>>(counts, pre, bsum);
        scan2_kernel<<<1, SCAN_BLK, 0, stream>>>(bsum, boff);
        scan3_kernel<<<SCAN_BLK, SCAN_T, 0, stream>>>(pre, boff, offs);
        scatter_kernel<<<pblocks, 256, 0, stream>>>(x, offs, sorted, N);
        encode_sorted_kernel<<<blocks, 256, 0, stream>>>(sorted, plane_t, line_t, out, N);
    } else if (ws_size >= need_mid) {
        __half* plane_t = (__half*)d_ws;
        __half* line_t  = plane_t + plane_t_elems;
        unsigned total  = N * 36u;
        unsigned blocks = (total + 255u) / 256u;
        tp_tables_kernel<<<tpblocks, 256, 0, stream>>>(plane, line, plane_t, line_t);
        encode_kernel<<<blocks, 256, 0, stream>>>(x, plane_t, line_t, out, N);
    } else {
        unsigned total  = N * 36u;
        unsigned blocks = (total + 255u) / 256u;
        encode_fallback_kernel<<<blocks, 256, 0, stream>>>(x, plane, line, out, N);
    }
}

// Round 7
// 263.462 us; speedup vs baseline: 1.7106x; 1.0396x over previous
//
#include <hip/hip_runtime.h>
#include <hip/hip_fp16.h>

#define RES 300
#define NC 48
#define RES2 (RES * RES)
#define CELLS 64                    // cells per axis
#define NBINS (CELLS*CELLS*CELLS)   // 262144 Morton cells
#define SCAN_T 1024
#define SCAN_BLK (NBINS / SCAN_T)   // 256
#define PPB 32                      // points per encode block
#define EBLK 192                    // 32 pts x 6 threads
#define ROWC 37                     // padded row stride in f32x4 chunks (36 + 1)

typedef float f32x4 __attribute__((ext_vector_type(4)));
typedef unsigned int u32x4 __attribute__((ext_vector_type(4)));

struct alignas(8)  h4 { __half2 h[2]; };
struct alignas(16) h8 { __half2 h[4]; };

__device__ __forceinline__ int clampi(int v, int lo, int hi) {
    return v < lo ? lo : (v > hi ? hi : v);
}

// spread up to 10 bits: bit i -> bit 3i
__device__ __forceinline__ unsigned spread3(unsigned v) {
    v = (v | (v << 16)) & 0x030000FFu;
    v = (v | (v << 8))  & 0x0300F00Fu;
    v = (v | (v << 4))  & 0x030C30C3u;
    v = (v | (v << 2))  & 0x09249249u;
    return v;
}

__device__ __forceinline__ unsigned morton_key(float a, float b, float c) {
    unsigned ca = (unsigned)clampi((int)(a * (float)CELLS), 0, CELLS - 1);
    unsigned cb = (unsigned)clampi((int)(b * (float)CELLS), 0, CELLS - 1);
    unsigned cc = (unsigned)clampi((int)(c * (float)CELLS), 0, CELLS - 1);
    return spread3(ca) | (spread3(cb) << 1) | (spread3(cc) << 2);
}

// ---------------- table transpose (fp32 channel-major -> fp16 channel-last), fused ----------------

__global__ __launch_bounds__(256) void tp_tables_kernel(const float* __restrict__ pin,
                                                        const float* __restrict__ lin,
                                                        __half* __restrict__ pout,
                                                        __half* __restrict__ lout) {
    unsigned idx = blockIdx.x * 256u + threadIdx.x;
    if (idx < 3u * RES2) {
        unsigned p  = idx / RES2;
        unsigned yx = idx - p * RES2;
        const float* src = pin + (size_t)p * NC * RES2 + yx;
        unsigned short v[NC];
#pragma unroll
        for (int c = 0; c < NC; ++c) {
            __half h = __float2half(src[(size_t)c * RES2]);
            v[c] = *reinterpret_cast<unsigned short*>(&h);
        }
        u32x4* dst = reinterpret_cast<u32x4*>(pout + (size_t)idx * NC);
#pragma unroll
        for (int i = 0; i < 6; ++i) {
            u32x4 w;
            w.x = (unsigned)v[8 * i + 0] | ((unsigned)v[8 * i + 1] << 16);
            w.y = (unsigned)v[8 * i + 2] | ((unsigned)v[8 * i + 3] << 16);
            w.z = (unsigned)v[8 * i + 4] | ((unsigned)v[8 * i + 5] << 16);
            w.w = (unsigned)v[8 * i + 6] | ((unsigned)v[8 * i + 7] << 16);
            dst[i] = w;
        }
    } else {
        unsigned li = idx - 3u * RES2;
        if (li >= 3u * RES) return;
        unsigned p = li / RES;
        unsigned y = li - p * RES;
#pragma unroll
        for (int c = 0; c < NC; ++c)
            lout[(size_t)li * NC + c] = __float2half(lin[((size_t)p * NC + c) * RES + y]);
    }
}

// ---------------- Morton counting sort ----------------

__global__ __launch_bounds__(256) void zero_bins_kernel(unsigned* __restrict__ counts) {
    unsigned i = blockIdx.x * 256u + threadIdx.x;
    if (i < NBINS) counts[i] = 0u;
}

__global__ __launch_bounds__(256) void hist_kernel(const float* __restrict__ x,
                                                   unsigned* __restrict__ counts,
                                                   unsigned N) {
    unsigned i = blockIdx.x * 256u + threadIdx.x;
    if (i >= N) return;
    unsigned k = morton_key(x[3u * i], x[3u * i + 1u], x[3u * i + 2u]);
    atomicAdd(&counts[k], 1u);
}

// stage 1: per-block (1024 bins) exclusive scan + block sum
__global__ __launch_bounds__(SCAN_T) void scan1_kernel(const unsigned* __restrict__ counts,
                                                       unsigned* __restrict__ pre,
                                                       unsigned* __restrict__ bsum) {
    __shared__ unsigned part[SCAN_T];
    unsigned b = blockIdx.x * SCAN_T + threadIdx.x;
    int t = threadIdx.x;
    unsigned c = counts[b];
    part[t] = c;
    __syncthreads();
    for (int d = 1; d < SCAN_T; d <<= 1) {
        unsigned v = (t >= d) ? part[t - d] : 0u;
        __syncthreads();
        part[t] += v;
        __syncthreads();
    }
    pre[b] = part[t] - c;
    if (t == SCAN_T - 1) bsum[blockIdx.x] = part[t];
}

// stage 2: one block, exclusive scan of SCAN_BLK block sums
__global__ __launch_bounds__(SCAN_BLK) void scan2_kernel(unsigned* __restrict__ bsum,
                                                         unsigned* __restrict__ boff) {
    __shared__ unsigned part[SCAN_BLK];
    int t = threadIdx.x;
    unsigned c = bsum[t];
    part[t] = c;
    __syncthreads();
    for (int d = 1; d < SCAN_BLK; d <<= 1) {
        unsigned v = (t >= d) ? part[t - d] : 0u;
        __syncthreads();
        part[t] += v;
        __syncthreads();
    }
    boff[t] = part[t] - c;
}

// stage 3: offs = pre + boff[blk]
__global__ __launch_bounds__(SCAN_T) void scan3_kernel(const unsigned* __restrict__ pre,
                                                       const unsigned* __restrict__ boff,
                                                       unsigned* __restrict__ offs) {
    unsigned b = blockIdx.x * SCAN_T + threadIdx.x;
    offs[b] = pre[b] + boff[blockIdx.x];
}

// scatter points into Morton order; offs is consumed (becomes end offsets)
__global__ __launch_bounds__(256) void scatter_kernel(const float* __restrict__ x,
                                                      unsigned* __restrict__ offs,
                                                      f32x4* __restrict__ sorted,
                                                      unsigned N) {
    unsigned i = blockIdx.x * 256u + threadIdx.x;
    if (i >= N) return;
    float a = x[3u * i], b = x[3u * i + 1u], c = x[3u * i + 2u];
    unsigned k = morton_key(a, b, c);
    unsigned pos = atomicAdd(&offs[k], 1u);
    f32x4 v;
    v.x = a; v.y = b; v.z = c; v.w = __uint_as_float(i);
    sorted[pos] = v;
}

// ---------------- encode: 6 threads/pt, 16B gathers, LDS store-transpose ----------------

__global__ __launch_bounds__(EBLK) void encode_sorted_kernel(const f32x4* __restrict__ sorted,
                                                             const __half* __restrict__ pt,  // (3,RES,RES,NC)
                                                             const __half* __restrict__ lt,  // (3,RES,NC)
                                                             float* __restrict__ out,
                                                             unsigned N) {
    // bijective XCD chunking: contiguous Morton range per XCD -> compact L2 working set
    unsigned nwg  = gridDim.x;
    unsigned orig = blockIdx.x;
    unsigned xcd = orig & 7u, j0 = orig >> 3u;
    unsigned qq = nwg >> 3u, rr = nwg & 7u;
    unsigned bid = (xcd < rr ? xcd * (qq + 1u) : rr * (qq + 1u) + (xcd - rr) * qq) + j0;

    __shared__ f32x4 fbuf[PPB * ROWC];   // padded row stride to spread LDS banks
    __shared__ unsigned nbuf[PPB];

    unsigned t   = threadIdx.x;
    unsigned ptl = t / 6u;
    unsigned c8  = t - ptl * 6u;       // 8-channel group
    unsigned B0  = bid * PPB;
    unsigned s   = B0 + ptl;

    if (s < N) {
        f32x4 pv4 = sorted[s];
        unsigned n = __float_as_uint(pv4.w);
        if (c8 == 0u) nbuf[ptl] = n;
        float xs0 = pv4.x, xs1 = pv4.y, xs2 = pv4.z;
        unsigned cb = c8 * 8u;

#pragma unroll
        for (int p = 0; p < 3; ++p) {
            float gxv = (p == 2) ? xs1 : xs0;
            float gyv = (p == 0) ? xs1 : xs2;
            float glv = (p == 0) ? xs2 : ((p == 1) ? xs1 : xs0);

            // mirror reference fp32 arithmetic
            float gxs = 2.0f * gxv - 1.0f;
            float gys = 2.0f * gyv - 1.0f;
            float gls = 2.0f * glv - 1.0f;
            float px = (gxs + 1.0f) * 0.5f * (float)(RES - 1);
            float py = (gys + 1.0f) * 0.5f * (float)(RES - 1);
            float pl = (gls + 1.0f) * 0.5f * (float)(RES - 1);

            float x0f = floorf(px), y0f = floorf(py), l0f = floorf(pl);
            float wx = px - x0f, wy = py - y0f, wl = pl - l0f;

            int ix0 = clampi((int)x0f, 0, RES - 1);
            int ix1 = ix0 + 1 > RES - 1 ? RES - 1 : ix0 + 1;
            int iy0 = clampi((int)y0f, 0, RES - 1);
            int iy1 = iy0 + 1 > RES - 1 ? RES - 1 : iy0 + 1;
            int il0 = clampi((int)l0f, 0, RES - 1);
            int il1 = il0 + 1 > RES - 1 ? RES - 1 : il0 + 1;

            const __half* pb = pt + (size_t)p * RES2 * NC;
            const __half* lb = lt + (size_t)p * RES * NC + cb;
            unsigned o00 = ((unsigned)iy0 * RES + (unsigned)ix0) * NC + cb;
            unsigned o01 = ((unsigned)iy0 * RES + (unsigned)ix1) * NC + cb;
            unsigned o10 = ((unsigned)iy1 * RES + (unsigned)ix0) * NC + cb;
            unsigned o11 = ((unsigned)iy1 * RES + (unsigned)ix1) * NC + cb;

            h8 v00 = *reinterpret_cast<const h8*>(pb + o00);
            h8 v01 = *reinterpret_cast<const h8*>(pb + o01);
            h8 v10 = *reinterpret_cast<const h8*>(pb + o10);
            h8 v11 = *reinterpret_cast<const h8*>(pb + o11);
            h8 vl0 = *reinterpret_cast<const h8*>(lb + (size_t)il0 * NC);
            h8 vl1 = *reinterpret_cast<const h8*>(lb + (size_t)il1 * NC);

            float w00 = (1.0f - wx) * (1.0f - wy);
            float w01 = wx * (1.0f - wy);
            float w10 = (1.0f - wx) * wy;
            float w11 = wx * wy;
            float wl0 = 1.0f - wl;

            f32x4 r0, r1;
#pragma unroll
            for (int jj = 0; jj < 4; ++jj) {
                float2 a00 = __half22float2(v00.h[jj]);
                float2 a01 = __half22float2(v01.h[jj]);
                float2 a10 = __half22float2(v10.h[jj]);
                float2 a11 = __half22float2(v11.h[jj]);
                float2 b0  = __half22float2(vl0.h[jj]);
                float2 b1  = __half22float2(vl1.h[jj]);
                float pvx = a00.x * w00 + a01.x * w01 + a10.x * w10 + a11.x * w11;
                float pvy = a00.y * w00 + a01.y * w01 + a10.y * w10 + a11.y * w11;
                float lvx = b0.x * wl0 + b1.x * wl;
                float lvy = b0.y * wl0 + b1.y * wl;
                float rx = pvx * lvx;
                float ry = pvy * lvy;
                if (jj == 0) { r0.x = rx; r0.y = ry; }
                if (jj == 1) { r0.z = rx; r0.w = ry; }
                if (jj == 2) { r1.x = rx; r1.y = ry; }
                if (jj == 3) { r1.z = rx; r1.w = ry; }
            }

            f32x4* dst = &fbuf[ptl * ROWC + (unsigned)p * 12u + c8 * 2u];
            dst[0] = r0;
            dst[1] = r1;
        }
    }
    __syncthreads();

    // phase 2: linear LDS read -> dense NT global stores (per-row contiguous runs)
    unsigned rem = N - B0;
    unsigned vp = rem < PPB ? rem : PPB;
    unsigned nchunk = vp * 36u;
#pragma unroll
    for (int j = 0; j < 6; ++j) {
        unsigned c = (unsigned)j * EBLK + t;
        if (c < nchunk) {
            unsigned row = c / 36u;
            unsigned off = c - row * 36u;
            f32x4 v = fbuf[row * ROWC + off];
            __builtin_nontemporal_store(v, reinterpret_cast<f32x4*>(out + (size_t)nbuf[row] * 144u + off * 4u));
        }
    }
}

// ---------------- unsorted encode (fallback when ws fits only tables) ----------------

__global__ __launch_bounds__(256) void encode_kernel(const float* __restrict__ x,
                                                     const __half* __restrict__ pt,
                                                     const __half* __restrict__ lt,
                                                     float* __restrict__ out,
                                                     unsigned N) {
    unsigned gid = blockIdx.x * 256u + threadIdx.x;
    if (gid >= N * 36u) return;
    unsigned n  = gid / 36u;
    unsigned q  = gid - n * 36u;
    unsigned p  = q / 12u;
    unsigned c4 = q - p * 12u;

    float xv0 = x[3u * n + 0u];
    float xv1 = x[3u * n + 1u];
    float xv2 = x[3u * n + 2u];
    float gxv = (p == 2u) ? xv1 : xv0;
    float gyv = (p == 0u) ? xv1 : xv2;
    float glv = (p == 0u) ? xv2 : ((p == 1u) ? xv1 : xv0);

    float gxs = 2.0f * gxv - 1.0f;
    float gys = 2.0f * gyv - 1.0f;
    float gls = 2.0f * glv - 1.0f;
    float px = (gxs + 1.0f) * 0.5f * (float)(RES - 1);
    float py = (gys + 1.0f) * 0.5f * (float)(RES - 1);
    float pl = (gls + 1.0f) * 0.5f * (float)(RES - 1);

    float x0f = floorf(px), y0f = floorf(py), l0f = floorf(pl);
    float wx = px - x0f, wy = py - y0f, wl = pl - l0f;

    int ix0 = clampi((int)x0f, 0, RES - 1);
    int ix1 = ix0 + 1 > RES - 1 ? RES - 1 : ix0 + 1;
    int iy0 = clampi((int)y0f, 0, RES - 1);
    int iy1 = iy0 + 1 > RES - 1 ? RES - 1 : iy0 + 1;
    int il0 = clampi((int)l0f, 0, RES - 1);
    int il1 = il0 + 1 > RES - 1 ? RES - 1 : il0 + 1;

    unsigned cbase = c4 * 4u;
    const __half* pb = pt + (size_t)p * RES2 * NC;
    h4 v00 = *reinterpret_cast<const h4*>(pb + ((unsigned)iy0 * RES + (unsigned)ix0) * NC + cbase);
    h4 v01 = *reinterpret_cast<const h4*>(pb + ((unsigned)iy0 * RES + (unsigned)ix1) * NC + cbase);
    h4 v10 = *reinterpret_cast<const h4*>(pb + ((unsigned)iy1 * RES + (unsigned)ix0) * NC + cbase);
    h4 v11 = *reinterpret_cast<const h4*>(pb + ((unsigned)iy1 * RES + (unsigned)ix1) * NC + cbase);

    float2 f00a = __half22float2(v00.h[0]), f00b = __half22float2(v00.h[1]);
    float2 f01a = __half22float2(v01.h[0]), f01b = __half22float2(v01.h[1]);
    float2 f10a = __half22float2(v10.h[0]), f10b = __half22float2(v10.h[1]);
    float2 f11a = __half22float2(v11.h[0]), f11b = __half22float2(v11.h[1]);

    float w00 = (1.0f - wx) * (1.0f - wy);
    float w01 = wx * (1.0f - wy);
    float w10 = (1.0f - wx) * wy;
    float w11 = wx * wy;

    f32x4 plane_v;
    plane_v.x = f00a.x * w00 + f01a.x * w01 + f10a.x * w10 + f11a.x * w11;
    plane_v.y = f00a.y * w00 + f01a.y * w01 + f10a.y * w10 + f11a.y * w11;
    plane_v.z = f00b.x * w00 + f01b.x * w01 + f10b.x * w10 + f11b.x * w11;
    plane_v.w = f00b.y * w00 + f01b.y * w01 + f10b.y * w10 + f11b.y * w11;

    const __half* lb = lt + (size_t)p * RES * NC + cbase;
    h4 vl0 = *reinterpret_cast<const h4*>(lb + (size_t)il0 * NC);
    h4 vl1 = *reinterpret_cast<const h4*>(lb + (size_t)il1 * NC);
    float2 l0a = __half22float2(vl0.h[0]), l0b = __half22float2(vl0.h[1]);
    float2 l1a = __half22float2(vl1.h[0]), l1b = __half22float2(vl1.h[1]);

    float wl0 = 1.0f - wl;
    f32x4 line_v;
    line_v.x = l0a.x * wl0 + l1a.x * wl;
    line_v.y = l0a.y * wl0 + l1a.y * wl;
    line_v.z = l0b.x * wl0 + l1b.x * wl;
    line_v.w = l0b.y * wl0 + l1b.y * wl;

    f32x4 rr = plane_v * line_v;
    __builtin_nontemporal_store(rr, reinterpret_cast<f32x4*>(out + (size_t)n * 144u + (size_t)q * 4u));
}

// last-resort fallback: gather from original channel-major layout
__global__ __launch_bounds__(256) void encode_fallback_kernel(const float* __restrict__ x,
                                                              const float* __restrict__ plane,
                                                              const float* __restrict__ line,
                                                              float* __restrict__ out,
                                                              unsigned N) {
    unsigned gid = blockIdx.x * 256u + threadIdx.x;
    if (gid >= N * 36u) return;
    unsigned n  = gid / 36u;
    unsigned q  = gid - n * 36u;
    unsigned p  = q / 12u;
    unsigned c4 = q - p * 12u;

    float xv0 = x[3u * n + 0u];
    float xv1 = x[3u * n + 1u];
    float xv2 = x[3u * n + 2u];
    float gxv = (p == 2u) ? xv1 : xv0;
    float gyv = (p == 0u) ? xv1 : xv2;
    float glv = (p == 0u) ? xv2 : ((p == 1u) ? xv1 : xv0);

    float gxs = 2.0f * gxv - 1.0f;
    float gys = 2.0f * gyv - 1.0f;
    float gls = 2.0f * glv - 1.0f;
    float px = (gxs + 1.0f) * 0.5f * (float)(RES - 1);
    float py = (gys + 1.0f) * 0.5f * (float)(RES - 1);
    float pl = (gls + 1.0f) * 0.5f * (float)(RES - 1);

    float x0f = floorf(px), y0f = floorf(py), l0f = floorf(pl);
    float wx = px - x0f, wy = py - y0f, wl = pl - l0f;

    int ix0 = clampi((int)x0f, 0, RES - 1);
    int ix1 = ix0 + 1 > RES - 1 ? RES - 1 : ix0 + 1;
    int iy0 = clampi((int)y0f, 0, RES - 1);
    int iy1 = iy0 + 1 > RES - 1 ? RES - 1 : iy0 + 1;
    int il0 = clampi((int)l0f, 0, RES - 1);
    int il1 = il0 + 1 > RES - 1 ? RES - 1 : il0 + 1;

    float w00 = (1.0f - wx) * (1.0f - wy);
    float w01 = wx * (1.0f - wy);
    float w10 = (1.0f - wx) * wy;
    float w11 = wx * wy;
    float wl0 = 1.0f - wl;

    float4 r;
    float* rp = &r.x;
#pragma unroll
    for (int cc = 0; cc < 4; ++cc) {
        unsigned c = c4 * 4u + (unsigned)cc;
        const float* pp = plane + ((size_t)p * NC + c) * RES2;
        float f00 = pp[(size_t)iy0 * RES + ix0];
        float f01 = pp[(size_t)iy0 * RES + ix1];
        float f10 = pp[(size_t)iy1 * RES + ix0];
        float f11 = pp[(size_t)iy1 * RES + ix1];
        float pv = f00 * w00 + f01 * w01 + f10 * w10 + f11 * w11;
        const float* lp = line + ((size_t)p * NC + c) * RES;
        float lv = lp[il0] * wl0 + lp[il1] * wl;
        rp[cc] = pv * lv;
    }
    *reinterpret_cast<float4*>(out + (size_t)n * 144u + (size_t)q * 4u) = r;
}

extern "C" void kernel_launch(void* const* d_in, const int* in_sizes, int n_in,
                              void* d_out, int out_size, void* d_ws, size_t ws_size,
                              hipStream_t stream) {
    const float* x     = (const float*)d_in[0];
    const float* plane = (const float*)d_in[1];
    const float* line  = (const float*)d_in[2];
    float* out = (float*)d_out;
    unsigned N = (unsigned)(in_sizes[0] / 3);

    size_t plane_t_elems = (size_t)3 * RES2 * NC;
    size_t line_t_elems  = (size_t)3 * RES * NC;
    size_t sorted_bytes  = (size_t)N * 16u;
    size_t plane_bytes   = plane_t_elems * sizeof(__half);
    size_t line_bytes    = line_t_elems * sizeof(__half);
    size_t bins_bytes    = (size_t)NBINS * 4u;
    size_t bsum_bytes    = (size_t)SCAN_BLK * 4u;

    size_t need_mid  = plane_bytes + line_bytes;
    size_t need_full = sorted_bytes + plane_bytes + line_bytes + 3u * bins_bytes + 2u * bsum_bytes;

    unsigned pblocks  = (N + 255u) / 256u;
    unsigned tpblocks = (3u * RES2 + 3u * RES + 255u) / 256u;

    if (ws_size >= need_full) {
        char* base = (char*)d_ws;
        f32x4*   sorted  = (f32x4*)base;    base += sorted_bytes;
        __half*  plane_t = (__half*)base;   base += plane_bytes;
        __half*  line_t  = (__half*)base;   base += line_bytes;
        unsigned* counts = (unsigned*)base; base += bins_bytes;
        unsigned* pre    = (unsigned*)base; base += bins_bytes;
        unsigned* offs   = (unsigned*)base; base += bins_bytes;
        unsigned* bsum   = (unsigned*)base; base += bsum_bytes;
        unsigned* boff   = (unsigned*)base;

        unsigned eblocks = (N + PPB - 1u) / PPB;

        zero_bins_kernel<<<(NBINS + 255) / 256, 256, 0, stream>>>(counts);
        hist_kernel<<<pblocks, 256, 0, stream>>>(x, counts, N);
        tp_tables_kernel<<<tpblocks, 256, 0, stream>>>(plane, line, plane_t, line_t);
        scan1_kernel<<<SCAN_BLK, SCAN_T, 0, stream>>>(counts, pre, bsum);
        scan2_kernel<<<1, SCAN_BLK, 0, stream>>>(bsum, boff);
        scan3_kernel<<<SCAN_BLK, SCAN_T, 0, stream>>>(pre, boff, offs);
        scatter_kernel<<<pblocks, 256, 0, stream>>>(x, offs, sorted, N);
        encode_sorted_kernel<<<eblocks, EBLK, 0, stream>>>(sorted, plane_t, line_t, out, N);
    } else if (ws_size >= need_mid) {
        __half* plane_t = (__half*)d_ws;
        __half* line_t  = plane_t + plane_t_elems;
        unsigned total  = N * 36u;
        unsigned blocks = (total + 255u) / 256u;
        tp_tables_kernel<<<tpblocks, 256, 0, stream>>>(plane, line, plane_t, line_t);
        encode_kernel<<<blocks, 256, 0, stream>>>(x, plane_t, line_t, out, N);
    } else {
        unsigned total  = N * 36u;
        unsigned blocks = (total + 255u) / 256u;
        encode_fallback_kernel<<<blocks, 256, 0, stream>>>(x, plane, line, out, N);
    }
}

// Round 8
// 261.404 us; speedup vs baseline: 1.7241x; 1.0079x over previous
//
#include <hip/hip_runtime.h>
#include <hip/hip_fp16.h>

#define RES 300
#define NC 48
#define RES2 (RES * RES)
#define CELLS 64                    // cells per axis
#define NBINS (CELLS*CELLS*CELLS)   // 262144 Morton cells
#define SCAN_T 1024
#define SCAN_BLK (NBINS / SCAN_T)   // 256
#define PPB 64                      // points per encode block
#define EBLK 384                    // 64 pts x 6 threads
#define ROWC 37                     // padded row stride in f32x4 chunks (36 + 1)

typedef float f32x4 __attribute__((ext_vector_type(4)));
typedef unsigned int u32x4 __attribute__((ext_vector_type(4)));

struct alignas(8)  h4 { __half2 h[2]; };
struct alignas(16) h8 { __half2 h[4]; };

__device__ __forceinline__ int clampi(int v, int lo, int hi) {
    return v < lo ? lo : (v > hi ? hi : v);
}

// spread up to 10 bits: bit i -> bit 3i
__device__ __forceinline__ unsigned spread3(unsigned v) {
    v = (v | (v << 16)) & 0x030000FFu;
    v = (v | (v << 8))  & 0x0300F00Fu;
    v = (v | (v << 4))  & 0x030C30C3u;
    v = (v | (v << 2))  & 0x09249249u;
    return v;
}

__device__ __forceinline__ unsigned morton_key(float a, float b, float c) {
    unsigned ca = (unsigned)clampi((int)(a * (float)CELLS), 0, CELLS - 1);
    unsigned cb = (unsigned)clampi((int)(b * (float)CELLS), 0, CELLS - 1);
    unsigned cc = (unsigned)clampi((int)(c * (float)CELLS), 0, CELLS - 1);
    return spread3(ca) | (spread3(cb) << 1) | (spread3(cc) << 2);
}

// ---------------- fused: table transpose + zero bins ----------------

__global__ __launch_bounds__(256) void tp_tables_kernel(const float* __restrict__ pin,
                                                        const float* __restrict__ lin,
                                                        __half* __restrict__ pout,
                                                        __half* __restrict__ lout,
                                                        unsigned* __restrict__ counts) {
    unsigned idx = blockIdx.x * 256u + threadIdx.x;
    if (idx < NBINS) counts[idx] = 0u;
    if (idx < 3u * RES2) {
        unsigned p  = idx / RES2;
        unsigned yx = idx - p * RES2;
        const float* src = pin + (size_t)p * NC * RES2 + yx;
        unsigned short v[NC];
#pragma unroll
        for (int c = 0; c < NC; ++c) {
            __half h = __float2half(src[(size_t)c * RES2]);
            v[c] = *reinterpret_cast<unsigned short*>(&h);
        }
        u32x4* dst = reinterpret_cast<u32x4*>(pout + (size_t)idx * NC);
#pragma unroll
        for (int i = 0; i < 6; ++i) {
            u32x4 w;
            w.x = (unsigned)v[8 * i + 0] | ((unsigned)v[8 * i + 1] << 16);
            w.y = (unsigned)v[8 * i + 2] | ((unsigned)v[8 * i + 3] << 16);
            w.z = (unsigned)v[8 * i + 4] | ((unsigned)v[8 * i + 5] << 16);
            w.w = (unsigned)v[8 * i + 6] | ((unsigned)v[8 * i + 7] << 16);
            dst[i] = w;
        }
    } else {
        unsigned li = idx - 3u * RES2;
        if (li >= 3u * RES) return;
        unsigned p = li / RES;
        unsigned y = li - p * RES;
#pragma unroll
        for (int c = 0; c < NC; ++c)
            lout[(size_t)li * NC + c] = __float2half(lin[((size_t)p * NC + c) * RES + y]);
    }
}

// ---------------- Morton counting sort ----------------

__global__ __launch_bounds__(256) void hist_kernel(const float* __restrict__ x,
                                                   unsigned* __restrict__ counts,
                                                   unsigned N) {
    unsigned i = blockIdx.x * 256u + threadIdx.x;
    if (i >= N) return;
    unsigned k = morton_key(x[3u * i], x[3u * i + 1u], x[3u * i + 2u]);
    atomicAdd(&counts[k], 1u);
}

// stage 1: per-block (1024 bins) exclusive scan + block sum
__global__ __launch_bounds__(SCAN_T) void scan1_kernel(const unsigned* __restrict__ counts,
                                                       unsigned* __restrict__ pre,
                                                       unsigned* __restrict__ bsum) {
    __shared__ unsigned part[SCAN_T];
    unsigned b = blockIdx.x * SCAN_T + threadIdx.x;
    int t = threadIdx.x;
    unsigned c = counts[b];
    part[t] = c;
    __syncthreads();
    for (int d = 1; d < SCAN_T; d <<= 1) {
        unsigned v = (t >= d) ? part[t - d] : 0u;
        __syncthreads();
        part[t] += v;
        __syncthreads();
    }
    pre[b] = part[t] - c;
    if (t == SCAN_T - 1) bsum[blockIdx.x] = part[t];
}

// stage 2 (fused): each block scans all SCAN_BLK block sums in LDS, adds its own prefix
__global__ __launch_bounds__(SCAN_T) void scan3_kernel(const unsigned* __restrict__ pre,
                                                       const unsigned* __restrict__ bsum,
                                                       unsigned* __restrict__ offs) {
    __shared__ unsigned part[SCAN_BLK];
    int t = threadIdx.x;
    if (t < SCAN_BLK) part[t] = bsum[t];
    __syncthreads();
    for (int d = 1; d < SCAN_BLK; d <<= 1) {
        unsigned v = 0u;
        if (t < SCAN_BLK && t >= d) v = part[t - d];
        __syncthreads();
        if (t < SCAN_BLK) part[t] += v;
        __syncthreads();
    }
    unsigned boff = (blockIdx.x == 0u) ? 0u : part[blockIdx.x - 1u];
    unsigned b = blockIdx.x * SCAN_T + threadIdx.x;
    offs[b] = pre[b] + boff;
}

// scatter points into Morton order; offs is consumed (becomes end offsets)
__global__ __launch_bounds__(256) void scatter_kernel(const float* __restrict__ x,
                                                      unsigned* __restrict__ offs,
                                                      f32x4* __restrict__ sorted,
                                                      unsigned N) {
    unsigned i = blockIdx.x * 256u + threadIdx.x;
    if (i >= N) return;
    float a = x[3u * i], b = x[3u * i + 1u], c = x[3u * i + 2u];
    unsigned k = morton_key(a, b, c);
    unsigned pos = atomicAdd(&offs[k], 1u);
    f32x4 v;
    v.x = a; v.y = b; v.z = c; v.w = __uint_as_float(i);
    sorted[pos] = v;
}

// ---------------- encode: 6 threads/pt, 16B gathers, LDS store-transpose ----------------

__global__ __launch_bounds__(EBLK) void encode_sorted_kernel(const f32x4* __restrict__ sorted,
                                                             const __half* __restrict__ pt,  // (3,RES,RES,NC)
                                                             const __half* __restrict__ lt,  // (3,RES,NC)
                                                             float* __restrict__ out,
                                                             unsigned N) {
    // bijective XCD chunking: contiguous Morton range per XCD -> compact L2 working set
    unsigned nwg  = gridDim.x;
    unsigned orig = blockIdx.x;
    unsigned xcd = orig & 7u, j0 = orig >> 3u;
    unsigned qq = nwg >> 3u, rr = nwg & 7u;
    unsigned bid = (xcd < rr ? xcd * (qq + 1u) : rr * (qq + 1u) + (xcd - rr) * qq) + j0;

    __shared__ f32x4 fbuf[PPB * ROWC];   // padded row stride to spread LDS banks
    __shared__ unsigned nbuf[PPB];

    unsigned t   = threadIdx.x;
    unsigned ptl = t / 6u;
    unsigned c8  = t - ptl * 6u;       // 8-channel group
    unsigned B0  = bid * PPB;
    unsigned s   = B0 + ptl;

    if (s < N) {
        f32x4 pv4 = sorted[s];
        unsigned n = __float_as_uint(pv4.w);
        if (c8 == 0u) nbuf[ptl] = n;
        float xs0 = pv4.x, xs1 = pv4.y, xs2 = pv4.z;
        unsigned cb = c8 * 8u;

#pragma unroll
        for (int p = 0; p < 3; ++p) {
            float gxv = (p == 2) ? xs1 : xs0;
            float gyv = (p == 0) ? xs1 : xs2;
            float glv = (p == 0) ? xs2 : ((p == 1) ? xs1 : xs0);

            // mirror reference fp32 arithmetic
            float gxs = 2.0f * gxv - 1.0f;
            float gys = 2.0f * gyv - 1.0f;
            float gls = 2.0f * glv - 1.0f;
            float px = (gxs + 1.0f) * 0.5f * (float)(RES - 1);
            float py = (gys + 1.0f) * 0.5f * (float)(RES - 1);
            float pl = (gls + 1.0f) * 0.5f * (float)(RES - 1);

            float x0f = floorf(px), y0f = floorf(py), l0f = floorf(pl);
            float wx = px - x0f, wy = py - y0f, wl = pl - l0f;

            int ix0 = clampi((int)x0f, 0, RES - 1);
            int ix1 = ix0 + 1 > RES - 1 ? RES - 1 : ix0 + 1;
            int iy0 = clampi((int)y0f, 0, RES - 1);
            int iy1 = iy0 + 1 > RES - 1 ? RES - 1 : iy0 + 1;
            int il0 = clampi((int)l0f, 0, RES - 1);
            int il1 = il0 + 1 > RES - 1 ? RES - 1 : il0 + 1;

            const __half* pb = pt + (size_t)p * RES2 * NC;
            const __half* lb = lt + (size_t)p * RES * NC + cb;
            unsigned o00 = ((unsigned)iy0 * RES + (unsigned)ix0) * NC + cb;
            unsigned o01 = ((unsigned)iy0 * RES + (unsigned)ix1) * NC + cb;
            unsigned o10 = ((unsigned)iy1 * RES + (unsigned)ix0) * NC + cb;
            unsigned o11 = ((unsigned)iy1 * RES + (unsigned)ix1) * NC + cb;

            h8 v00 = *reinterpret_cast<const h8*>(pb + o00);
            h8 v01 = *reinterpret_cast<const h8*>(pb + o01);
            h8 v10 = *reinterpret_cast<const h8*>(pb + o10);
            h8 v11 = *reinterpret_cast<const h8*>(pb + o11);
            h8 vl0 = *reinterpret_cast<const h8*>(lb + (size_t)il0 * NC);
            h8 vl1 = *reinterpret_cast<const h8*>(lb + (size_t)il1 * NC);

            float w00 = (1.0f - wx) * (1.0f - wy);
            float w01 = wx * (1.0f - wy);
            float w10 = (1.0f - wx) * wy;
            float w11 = wx * wy;
            float wl0 = 1.0f - wl;

            f32x4 r0, r1;
#pragma unroll
            for (int jj = 0; jj < 4; ++jj) {
                float2 a00 = __half22float2(v00.h[jj]);
                float2 a01 = __half22float2(v01.h[jj]);
                float2 a10 = __half22float2(v10.h[jj]);
                float2 a11 = __half22float2(v11.h[jj]);
                float2 b0  = __half22float2(vl0.h[jj]);
                float2 b1  = __half22float2(vl1.h[jj]);
                float pvx = a00.x * w00 + a01.x * w01 + a10.x * w10 + a11.x * w11;
                float pvy = a00.y * w00 + a01.y * w01 + a10.y * w10 + a11.y * w11;
                float lvx = b0.x * wl0 + b1.x * wl;
                float lvy = b0.y * wl0 + b1.y * wl;
                float rx = pvx * lvx;
                float ry = pvy * lvy;
                if (jj == 0) { r0.x = rx; r0.y = ry; }
                if (jj == 1) { r0.z = rx; r0.w = ry; }
                if (jj == 2) { r1.x = rx; r1.y = ry; }
                if (jj == 3) { r1.z = rx; r1.w = ry; }
            }

            f32x4* dst = &fbuf[ptl * ROWC + (unsigned)p * 12u + c8 * 2u];
            dst[0] = r0;
            dst[1] = r1;
        }
    }
    __syncthreads();

    // phase 2: linear LDS read -> dense NT global stores (per-row contiguous runs)
    unsigned rem = N - B0;
    unsigned vp = rem < PPB ? rem : PPB;
    unsigned nchunk = vp * 36u;
#pragma unroll
    for (int j = 0; j < 6; ++j) {
        unsigned c = (unsigned)j * EBLK + t;
        if (c < nchunk) {
            unsigned row = c / 36u;
            unsigned off = c - row * 36u;
            f32x4 v = fbuf[row * ROWC + off];
            __builtin_nontemporal_store(v, reinterpret_cast<f32x4*>(out + (size_t)nbuf[row] * 144u + off * 4u));
        }
    }
}

// ---------------- unsorted encode (fallback when ws fits only tables) ----------------

__global__ __launch_bounds__(256) void encode_kernel(const float* __restrict__ x,
                                                     const __half* __restrict__ pt,
                                                     const __half* __restrict__ lt,
                                                     float* __restrict__ out,
                                                     unsigned N) {
    unsigned gid = blockIdx.x * 256u + threadIdx.x;
    if (gid >= N * 36u) return;
    unsigned n  = gid / 36u;
    unsigned q  = gid - n * 36u;
    unsigned p  = q / 12u;
    unsigned c4 = q - p * 12u;

    float xv0 = x[3u * n + 0u];
    float xv1 = x[3u * n + 1u];
    float xv2 = x[3u * n + 2u];
    float gxv = (p == 2u) ? xv1 : xv0;
    float gyv = (p == 0u) ? xv1 : xv2;
    float glv = (p == 0u) ? xv2 : ((p == 1u) ? xv1 : xv0);

    float gxs = 2.0f * gxv - 1.0f;
    float gys = 2.0f * gyv - 1.0f;
    float gls = 2.0f * glv - 1.0f;
    float px = (gxs + 1.0f) * 0.5f * (float)(RES - 1);
    float py = (gys + 1.0f) * 0.5f * (float)(RES - 1);
    float pl = (gls + 1.0f) * 0.5f * (float)(RES - 1);

    float x0f = floorf(px), y0f = floorf(py), l0f = floorf(pl);
    float wx = px - x0f, wy = py - y0f, wl = pl - l0f;

    int ix0 = clampi((int)x0f, 0, RES - 1);
    int ix1 = ix0 + 1 > RES - 1 ? RES - 1 : ix0 + 1;
    int iy0 = clampi((int)y0f, 0, RES - 1);
    int iy1 = iy0 + 1 > RES - 1 ? RES - 1 : iy0 + 1;
    int il0 = clampi((int)l0f, 0, RES - 1);
    int il1 = il0 + 1 > RES - 1 ? RES - 1 : il0 + 1;

    unsigned cbase = c4 * 4u;
    const __half* pb = pt + (size_t)p * RES2 * NC;
    h4 v00 = *reinterpret_cast<const h4*>(pb + ((unsigned)iy0 * RES + (unsigned)ix0) * NC + cbase);
    h4 v01 = *reinterpret_cast<const h4*>(pb + ((unsigned)iy0 * RES + (unsigned)ix1) * NC + cbase);
    h4 v10 = *reinterpret_cast<const h4*>(pb + ((unsigned)iy1 * RES + (unsigned)ix0) * NC + cbase);
    h4 v11 = *reinterpret_cast<const h4*>(pb + ((unsigned)iy1 * RES + (unsigned)ix1) * NC + cbase);

    float2 f00a = __half22float2(v00.h[0]), f00b = __half22float2(v00.h[1]);
    float2 f01a = __half22float2(v01.h[0]), f01b = __half22float2(v01.h[1]);
    float2 f10a = __half22float2(v10.h[0]), f10b = __half22float2(v10.h[1]);
    float2 f11a = __half22float2(v11.h[0]), f11b = __half22float2(v11.h[1]);

    float w00 = (1.0f - wx) * (1.0f - wy);
    float w01 = wx * (1.0f - wy);
    float w10 = (1.0f - wx) * wy;
    float w11 = wx * wy;

    f32x4 plane_v;
    plane_v.x = f00a.x * w00 + f01a.x * w01 + f10a.x * w10 + f11a.x * w11;
    plane_v.y = f00a.y * w00 + f01a.y * w01 + f10a.y * w10 + f11a.y * w11;
    plane_v.z = f00b.x * w00 + f01b.x * w01 + f10b.x * w10 + f11b.x * w11;
    plane_v.w = f00b.y * w00 + f01b.y * w01 + f10b.y * w10 + f11b.y * w11;

    const __half* lb = lt + (size_t)p * RES * NC + cbase;
    h4 vl0 = *reinterpret_cast<const h4*>(lb + (size_t)il0 * NC);
    h4 vl1 = *reinterpret_cast<const h4*>(lb + (size_t)il1 * NC);
    float2 l0a = __half22float2(vl0.h[0]), l0b = __half22float2(vl0.h[1]);
    float2 l1a = __half22float2(vl1.h[0]), l1b = __half22float2(vl1.h[1]);

    float wl0 = 1.0f - wl;
    f32x4 line_v;
    line_v.x = l0a.x * wl0 + l1a.x * wl;
    line_v.y = l0a.y * wl0 + l1a.y * wl;
    line_v.z = l0b.x * wl0 + l1b.x * wl;
    line_v.w = l0b.y * wl0 + l1b.y * wl;

    f32x4 rr = plane_v * line_v;
    __builtin_nontemporal_store(rr, reinterpret_cast<f32x4*>(out + (size_t)n * 144u + (size_t)q * 4u));
}

// last-resort fallback: gather from original channel-major layout
__global__ __launch_bounds__(256) void encode_fallback_kernel(const float* __restrict__ x,
                                                              const float* __restrict__ plane,
                                                              const float* __restrict__ line,
                                                              float* __restrict__ out,
                                                              unsigned N) {
    unsigned gid = blockIdx.x * 256u + threadIdx.x;
    if (gid >= N * 36u) return;
    unsigned n  = gid / 36u;
    unsigned q  = gid - n * 36u;
    unsigned p  = q / 12u;
    unsigned c4 = q - p * 12u;

    float xv0 = x[3u * n + 0u];
    float xv1 = x[3u * n + 1u];
    float xv2 = x[3u * n + 2u];
    float gxv = (p == 2u) ? xv1 : xv0;
    float gyv = (p == 0u) ? xv1 : xv2;
    float glv = (p == 0u) ? xv2 : ((p == 1u) ? xv1 : xv0);

    float gxs = 2.0f * gxv - 1.0f;
    float gys = 2.0f * gyv - 1.0f;
    float gls = 2.0f * glv - 1.0f;
    float px = (gxs + 1.0f) * 0.5f * (float)(RES - 1);
    float py = (gys + 1.0f) * 0.5f * (float)(RES - 1);
    float pl = (gls + 1.0f) * 0.5f * (float)(RES - 1);

    float x0f = floorf(px), y0f = floorf(py), l0f = floorf(pl);
    float wx = px - x0f, wy = py - y0f, wl = pl - l0f;

    int ix0 = clampi((int)x0f, 0, RES - 1);
    int ix1 = ix0 + 1 > RES - 1 ? RES - 1 : ix0 + 1;
    int iy0 = clampi((int)y0f, 0, RES - 1);
    int iy1 = iy0 + 1 > RES - 1 ? RES - 1 : iy0 + 1;
    int il0 = clampi((int)l0f, 0, RES - 1);
    int il1 = il0 + 1 > RES - 1 ? RES - 1 : il0 + 1;

    float w00 = (1.0f - wx) * (1.0f - wy);
    float w01 = wx * (1.0f - wy);
    float w10 = (1.0f - wx) * wy;
    float w11 = wx * wy;
    float wl0 = 1.0f - wl;

    float4 r;
    float* rp = &r.x;
#pragma unroll
    for (int cc = 0; cc < 4; ++cc) {
        unsigned c = c4 * 4u + (unsigned)cc;
        const float* pp = plane + ((size_t)p * NC + c) * RES2;
        float f00 = pp[(size_t)iy0 * RES + ix0];
        float f01 = pp[(size_t)iy0 * RES + ix1];
        float f10 = pp[(size_t)iy1 * RES + ix0];
        float f11 = pp[(size_t)iy1 * RES + ix1];
        float pv = f00 * w00 + f01 * w01 + f10 * w10 + f11 * w11;
        const float* lp = line + ((size_t)p * NC + c) * RES;
        float lv = lp[il0] * wl0 + lp[il1] * wl;
        rp[cc] = pv * lv;
    }
    *reinterpret_cast<float4*>(out + (size_t)n * 144u + (size_t)q * 4u) = r;
}

extern "C" void kernel_launch(void* const* d_in, const int* in_sizes, int n_in,
                              void* d_out, int out_size, void* d_ws, size_t ws_size,
                              hipStream_t stream) {
    const float* x     = (const float*)d_in[0];
    const float* plane = (const float*)d_in[1];
    const float* line  = (const float*)d_in[2];
    float* out = (float*)d_out;
    unsigned N = (unsigned)(in_sizes[0] / 3);

    size_t plane_t_elems = (size_t)3 * RES2 * NC;
    size_t line_t_elems  = (size_t)3 * RES * NC;
    size_t sorted_bytes  = (size_t)N * 16u;
    size_t plane_bytes   = plane_t_elems * sizeof(__half);
    size_t line_bytes    = line_t_elems * sizeof(__half);
    size_t bins_bytes    = (size_t)NBINS * 4u;
    size_t bsum_bytes    = (size_t)SCAN_BLK * 4u;

    size_t need_mid  = plane_bytes + line_bytes;
    size_t need_full = sorted_bytes + plane_bytes + line_bytes + 3u * bins_bytes + bsum_bytes;

    unsigned pblocks  = (N + 255u) / 256u;
    unsigned tpblocks = (3u * RES2 + 3u * RES + 255u) / 256u;

    if (ws_size >= need_full) {
        char* base = (char*)d_ws;
        f32x4*   sorted  = (f32x4*)base;    base += sorted_bytes;
        __half*  plane_t = (__half*)base;   base += plane_bytes;
        __half*  line_t  = (__half*)base;   base += line_bytes;
        unsigned* counts = (unsigned*)base; base += bins_bytes;
        unsigned* pre    = (unsigned*)base; base += bins_bytes;
        unsigned* offs   = (unsigned*)base; base += bins_bytes;
        unsigned* bsum   = (unsigned*)base;

        unsigned eblocks = (N + PPB - 1u) / PPB;

        tp_tables_kernel<<<tpblocks, 256, 0, stream>>>(plane, line, plane_t, line_t, counts);
        hist_kernel<<<pblocks, 256, 0, stream>>>(x, counts, N);
        scan1_kernel<<<SCAN_BLK, SCAN_T, 0, stream>>>(counts, pre, bsum);
        scan3_kernel<<<SCAN_BLK, SCAN_T, 0, stream>>>(pre, bsum, offs);
        scatter_kernel<<<pblocks, 256, 0, stream>>>(x, offs, sorted, N);
        encode_sorted_kernel<<<eblocks, EBLK, 0, stream>>>(sorted, plane_t, line_t, out, N);
    } else if (ws_size >= need_mid) {
        __half* plane_t = (__half*)d_ws;
        __half* line_t  = plane_t + plane_t_elems;
        unsigned total  = N * 36u;
        unsigned blocks = (total + 255u) / 256u;
        tp_tables_kernel<<<tpblocks, 256, 0, stream>>>(plane, line, plane_t, line_t, (unsigned*)d_ws);
        encode_kernel<<<blocks, 256, 0, stream>>>(x, plane_t, line_t, out, N);
    } else {
        unsigned total  = N * 36u;
        unsigned blocks = (total + 255u) / 256u;
        encode_fallback_kernel<<<blocks, 256, 0, stream>>>(x, plane, line, out, N);
    }
}